// Round 10
// baseline (912.943 us; speedup 1.0000x reference)
//
#include <hip/hip_runtime.h>
#include <hip/hip_fp16.h>

#define IN_DIM 128
#define NCLS 40
#define AS_STRIDE 136   // halves; 272 B row stride

// ---------------- degree / norm ----------------

__global__ __launch_bounds__(256) void deg_kernel(const int* __restrict__ src, const int* __restrict__ dst,
                                                  int* __restrict__ ds, int* __restrict__ dd, int E) {
    int e = blockIdx.x * 256 + threadIdx.x;
    if (e < E) {
        atomicAdd(&ds[src[e]], 1);
        atomicAdd(&dd[dst[e]], 1);
    }
}

__global__ __launch_bounds__(256) void norm_kernel(const int* __restrict__ ds, const int* __restrict__ dd,
                                                   float* __restrict__ ns, float* __restrict__ nd, int N) {
    int i = blockIdx.x * 256 + threadIdx.x;
    if (i < N) {
        ns[i] = ds[i] > 0 ? rsqrtf((float)ds[i]) : 0.f;
        nd[i] = dd[i] > 0 ? rsqrtf((float)dd[i]) : 0.f;
    }
}

// ---------------- exclusive scan of in-degrees -> row_ptr ----------------

__global__ __launch_bounds__(256) void scan_partial(const int* __restrict__ dd, int* __restrict__ bsums, int N) {
    __shared__ int sd[256];
    int t = threadIdx.x;
    int base = blockIdx.x * 1024 + t * 4;
    int s = 0;
#pragma unroll
    for (int k = 0; k < 4; ++k) { int i = base + k; if (i < N) s += dd[i]; }
    sd[t] = s;
    __syncthreads();
    for (int off = 128; off > 0; off >>= 1) {
        if (t < off) sd[t] += sd[t + off];
        __syncthreads();
    }
    if (t == 0) bsums[blockIdx.x] = sd[0];
}

__global__ __launch_bounds__(128) void scan_bsums(int* __restrict__ bsums, int nb) {
    __shared__ int sd[128];
    __shared__ int carry_s;
    int t = threadIdx.x;
    if (t == 0) carry_s = 0;
    __syncthreads();
    for (int base = 0; base < nb; base += 128) {
        int i = base + t;
        int orig = (i < nb) ? bsums[i] : 0;
        sd[t] = orig;
        __syncthreads();
        for (int off = 1; off < 128; off <<= 1) {
            int u = (t >= off) ? sd[t - off] : 0;
            __syncthreads();
            sd[t] += u;
            __syncthreads();
        }
        int carry = carry_s;
        if (i < nb) bsums[i] = carry + sd[t] - orig;   // exclusive
        __syncthreads();
        if (t == 127) carry_s = carry + sd[127];
        __syncthreads();
    }
}

__global__ __launch_bounds__(256) void scan_final(const int* __restrict__ dd, const int* __restrict__ bsums,
                                                  int* __restrict__ cursor, int N) {
    __shared__ int sd[256];
    int t = threadIdx.x;
    int base = blockIdx.x * 1024 + t * 4;
    int v[4]; int s = 0;
#pragma unroll
    for (int k = 0; k < 4; ++k) { int i = base + k; v[k] = (i < N) ? dd[i] : 0; s += v[k]; }
    sd[t] = s;
    __syncthreads();
    for (int off = 1; off < 256; off <<= 1) {
        int u = (t >= off) ? sd[t - off] : 0;
        __syncthreads();
        sd[t] += u;
        __syncthreads();
    }
    int excl = sd[t] - s + bsums[blockIdx.x];
#pragma unroll
    for (int k = 0; k < 4; ++k) {
        int i = base + k;
        if (i < N) cursor[i] = excl;
        excl += v[k];
    }
}

__global__ __launch_bounds__(256) void fill_csr(const int* __restrict__ src, const int* __restrict__ dst,
                                                int* __restrict__ cursor, int* __restrict__ csr, int E) {
    int e = blockIdx.x * 256 + threadIdx.x;
    if (e < E) {
        int slot = atomicAdd(&cursor[dst[e]], 1);
        csr[slot] = src[e];
    }
}

// ---------------- helpers ----------------

__device__ __forceinline__ float4 zero4() { return make_float4(0.f, 0.f, 0.f, 0.f); }

__device__ __forceinline__ void fma4(float4& acc, float s, const float4& wv) {
    acc.x = fmaf(s, wv.x, acc.x);
    acc.y = fmaf(s, wv.y, acc.y);
    acc.z = fmaf(s, wv.z, acc.z);
    acc.w = fmaf(s, wv.w, acc.w);
}

// accumulate 8 halves (one int4) into two float4s
__device__ __forceinline__ void add_h8(float4& a0, float4& a1, const int4& v) {
    const __half2* h = (const __half2*)&v;
    float2 f0 = __half22float2(h[0]);
    float2 f1 = __half22float2(h[1]);
    float2 f2 = __half22float2(h[2]);
    float2 f3 = __half22float2(h[3]);
    a0.x += f0.x; a0.y += f0.y; a0.z += f1.x; a0.w += f1.y;
    a1.x += f2.x; a1.y += f2.y; a1.z += f3.x; a1.w += f3.y;
}

__device__ __forceinline__ void acc_h8m(float4& a0, float4& a1, const int4& v, float m) {
    const __half2* h = (const __half2*)&v;
    float2 f0 = __half22float2(h[0]);
    float2 f1 = __half22float2(h[1]);
    float2 f2 = __half22float2(h[2]);
    float2 f3 = __half22float2(h[3]);
    a0.x = fmaf(f0.x, m, a0.x); a0.y = fmaf(f0.y, m, a0.y);
    a0.z = fmaf(f1.x, m, a0.z); a0.w = fmaf(f1.y, m, a0.w);
    a1.x = fmaf(f2.x, m, a1.x); a1.y = fmaf(f2.y, m, a1.y);
    a1.z = fmaf(f3.x, m, a1.z); a1.w = fmaf(f3.y, m, a1.w);
}

__device__ __forceinline__ int4 pack_h8(const float4& o0, const float4& o1) {
    int4 p;
    __half2* ph = (__half2*)&p;
    ph[0] = __float22half2_rn(make_float2(o0.x, o0.y));
    ph[1] = __float22half2_rn(make_float2(o0.z, o0.w));
    ph[2] = __float22half2_rn(make_float2(o1.x, o1.y));
    ph[3] = __float22half2_rn(make_float2(o1.z, o1.w));
    return p;
}

// ---------------- prescale: xh[i] = fp16(x[i] * ns[row]) ----------------

__global__ __launch_bounds__(256) void prescale_kernel(const float* __restrict__ x, const float* __restrict__ ns,
                                                       __half* __restrict__ xh, int N) {
    int tid = blockIdx.x * 256 + threadIdx.x;     // one per 8 floats
    if (tid >= N * 16) return;
    int row = tid >> 4;
    int c = tid & 15;
    float s = ns[row];
    const float4* xp = (const float4*)x + (size_t)row * 32 + c * 2;
    float4 v0 = xp[0], v1 = xp[1];
    v0.x *= s; v0.y *= s; v0.z *= s; v0.w *= s;
    v1.x *= s; v1.y *= s; v1.z *= s; v1.w *= s;
    ((int4*)xh)[tid] = pack_h8(v0, v1);
}

// ---------------- feature-sliced SpMM: agg[r][slice] = sum_{s in N(r)} x[s][slice] ----------------
// grid = nrb * 8; slice = bid & 7 (round-robin -> one XCD per slice; per-slice table
// N x 32 B = 3.2 MB fits the 4 MiB XCD L2). Block covers 128 rows; thread = (row, 16B half).
// Unroll-4 independent gathers per thread; fp32 accumulate; fp16 write (unscaled sum;
// nd folded into the GEMM epilogue).

__global__ __launch_bounds__(256) void spmm16(const __half* __restrict__ xh, const int* __restrict__ csr,
                                              const int* __restrict__ cursor, __half* __restrict__ agg, int N) {
    int bid = blockIdx.x;
    int slice = bid & 7;
    int rb = bid >> 3;
    int r = rb * 128 + (threadIdx.x >> 1);
    if (r >= N) return;
    int h = threadIdx.x & 1;
    int off = slice * 2 + h;             // int4 index within the 16-int4 row
    int start = r ? cursor[r - 1] : 0;
    int end = cursor[r];
    const int4* xi = (const int4*)xh;
    float4 a0 = zero4(), a1 = zero4();
    int e = start;
    for (; e + 4 <= end; e += 4) {
        int i0 = csr[e + 0], i1 = csr[e + 1], i2 = csr[e + 2], i3 = csr[e + 3];
        int4 v0 = xi[(size_t)i0 * 16 + off];
        int4 v1 = xi[(size_t)i1 * 16 + off];
        int4 v2 = xi[(size_t)i2 * 16 + off];
        int4 v3 = xi[(size_t)i3 * 16 + off];
        add_h8(a0, a1, v0); add_h8(a0, a1, v1);
        add_h8(a0, a1, v2); add_h8(a0, a1, v3);
    }
    for (; e < end; ++e) {
        int i0 = csr[e];
        int4 v0 = xi[(size_t)i0 * 16 + off];
        add_h8(a0, a1, v0);
    }
    ((int4*)agg)[(size_t)r * 16 + off] = pack_h8(a0, a1);
}

// ---------------- GEMM 128(fp16 agg) -> 128, epilogue acc*nd + bias, relu, (*ns) -> fp16 -------
// 64 rows/block, 256 threads; LDS-staged fp16 A tile; W fp32 from L2.

template<int SCALE_NS>
__global__ __launch_bounds__(256, 6) void gemm128h(const __half* __restrict__ agg, const float* __restrict__ nd,
                                                   const float* __restrict__ ns, const float* __restrict__ W,
                                                   const float* __restrict__ bias, __half* __restrict__ out, int N) {
    __shared__ __half As[64 * AS_STRIDE];
    int t = threadIdx.x;
    int row0 = blockIdx.x * 64;

    // stage 64 rows x 16 int4 (fp16)
#pragma unroll
    for (int i = 0; i < 4; ++i) {
        int idx = t + 256 * i;          // 0..1023
        int r = idx >> 4;
        int c = idx & 15;
        int gr = row0 + r;
        int4 v = make_int4(0, 0, 0, 0);
        if (gr < N) v = ((const int4*)agg)[(size_t)gr * 16 + c];
        *(int4*)&As[r * AS_STRIDE + c * 8] = v;
    }
    __syncthreads();

    int rg = t >> 4;
    int cgp = t & 15;
    int rbase = rg * 4;
    const float4* Wg = (const float4*)W;
    float4 acc[4][2];
#pragma unroll
    for (int m = 0; m < 4; ++m) { acc[m][0] = zero4(); acc[m][1] = zero4(); }
#pragma unroll 2
    for (int k4 = 0; k4 < 32; ++k4) {
        int k0 = k4 * 4;
        float4 a[4];
#pragma unroll
        for (int m = 0; m < 4; ++m) {
            uint2 raw = *(const uint2*)&As[(rbase + m) * AS_STRIDE + k0];
            const __half2* hp = (const __half2*)&raw;
            float2 f0 = __half22float2(hp[0]);
            float2 f1 = __half22float2(hp[1]);
            a[m] = make_float4(f0.x, f0.y, f1.x, f1.y);
        }
        float4 w[4][2];
#pragma unroll
        for (int j = 0; j < 4; ++j) {
            w[j][0] = Wg[(k0 + j) * 32 + cgp * 2 + 0];
            w[j][1] = Wg[(k0 + j) * 32 + cgp * 2 + 1];
        }
#pragma unroll
        for (int m = 0; m < 4; ++m) {
            fma4(acc[m][0], a[m].x, w[0][0]); fma4(acc[m][1], a[m].x, w[0][1]);
            fma4(acc[m][0], a[m].y, w[1][0]); fma4(acc[m][1], a[m].y, w[1][1]);
            fma4(acc[m][0], a[m].z, w[2][0]); fma4(acc[m][1], a[m].z, w[2][1]);
            fma4(acc[m][0], a[m].w, w[3][0]); fma4(acc[m][1], a[m].w, w[3][1]);
        }
    }

    float4 bb0 = ((const float4*)bias)[cgp * 2 + 0];
    float4 bb1 = ((const float4*)bias)[cgp * 2 + 1];
#pragma unroll
    for (int m = 0; m < 4; ++m) {
        int gr = row0 + rbase + m;
        if (gr < N) {
            float ndr = nd[gr];
            float4 o0, o1;
            o0.x = fmaxf(fmaf(acc[m][0].x, ndr, bb0.x), 0.f);
            o0.y = fmaxf(fmaf(acc[m][0].y, ndr, bb0.y), 0.f);
            o0.z = fmaxf(fmaf(acc[m][0].z, ndr, bb0.z), 0.f);
            o0.w = fmaxf(fmaf(acc[m][0].w, ndr, bb0.w), 0.f);
            o1.x = fmaxf(fmaf(acc[m][1].x, ndr, bb1.x), 0.f);
            o1.y = fmaxf(fmaf(acc[m][1].y, ndr, bb1.y), 0.f);
            o1.z = fmaxf(fmaf(acc[m][1].z, ndr, bb1.z), 0.f);
            o1.w = fmaxf(fmaf(acc[m][1].w, ndr, bb1.w), 0.f);
            if (SCALE_NS) {
                float s = ns[gr];
                o0.x *= s; o0.y *= s; o0.z *= s; o0.w *= s;
                o1.x *= s; o1.y *= s; o1.z *= s; o1.w *= s;
            }
            ((int4*)out)[(size_t)gr * 16 + cgp] = pack_h8(o0, o1);
        }
    }
}

// ---------------- GEMM 128(fp16) -> 40, epilogue *ns -> fp16 y (stride 40 halves) ----------

__global__ __launch_bounds__(256) void gemm40_kernel(const __half* __restrict__ A, const float* __restrict__ W,
                                                     const float* __restrict__ ns, __half* __restrict__ y, int N) {
    __shared__ float Ws[128 * NCLS];   // 20 KB
    __shared__ float As[32 * 132];     // 16.5 KB
    int t = threadIdx.x;
    int row0 = blockIdx.x * 32;

#pragma unroll
    for (int i = 0; i < 5; ++i) {
        int idx = t + 256 * i;
        ((float4*)Ws)[idx] = ((const float4*)W)[idx];
    }
#pragma unroll
    for (int i = 0; i < 2; ++i) {
        int idx = t + 256 * i;        // 0..511
        int r = idx >> 4;
        int c16 = idx & 15;
        int gr = row0 + r;
        int4 v = make_int4(0, 0, 0, 0);
        if (gr < N) v = ((const int4*)A)[(size_t)gr * 16 + c16];
        const __half2* h = (const __half2*)&v;
        float2 f0 = __half22float2(h[0]);
        float2 f1 = __half22float2(h[1]);
        float2 f2 = __half22float2(h[2]);
        float2 f3 = __half22float2(h[3]);
        float* dp = &As[r * 132 + c16 * 8];
        dp[0] = f0.x; dp[1] = f0.y; dp[2] = f1.x; dp[3] = f1.y;
        dp[4] = f2.x; dp[5] = f2.y; dp[6] = f3.x; dp[7] = f3.y;
    }
    __syncthreads();

    int row = t >> 3;
    int cg = t & 7;
    float acc[5] = {0.f, 0.f, 0.f, 0.f, 0.f};
#pragma unroll 2
    for (int k4 = 0; k4 < 32; ++k4) {
        float4 a = *(const float4*)&As[row * 132 + k4 * 4];
#pragma unroll
        for (int j = 0; j < 4; ++j) {
            float av = (j == 0) ? a.x : (j == 1) ? a.y : (j == 2) ? a.z : a.w;
            const float* wp = &Ws[(k4 * 4 + j) * NCLS + cg * 5];
            acc[0] = fmaf(av, wp[0], acc[0]);
            acc[1] = fmaf(av, wp[1], acc[1]);
            acc[2] = fmaf(av, wp[2], acc[2]);
            acc[3] = fmaf(av, wp[3], acc[3]);
            acc[4] = fmaf(av, wp[4], acc[4]);
        }
    }
    int gr = row0 + row;
    if (gr < N) {
        float s = ns[gr];
        __half* yp = y + (size_t)gr * NCLS + cg * 5;
        yp[0] = __float2half_rn(acc[0] * s);
        yp[1] = __float2half_rn(acc[1] * s);
        yp[2] = __float2half_rn(acc[2] * s);
        yp[3] = __float2half_rn(acc[3] * s);
        yp[4] = __float2half_rn(acc[4] * s);
    }
}

// ---------------- gather 40-d (fp16 y, pre-scaled by ns) + *nd + b2 -> out (fp32) ----------

__global__ __launch_bounds__(256) void gather40_finish(const __half* __restrict__ y, const int* __restrict__ csr,
                                                       const int* __restrict__ cursor, const float* __restrict__ nd,
                                                       const float* __restrict__ b2, float* __restrict__ out, int N) {
    int t = threadIdx.x;
    int lane = t & 63;
    int r = blockIdx.x * 4 + (t >> 6);
    if (r >= N) return;
    int g = lane >> 3;
    int c = lane & 7;
    int start = r ? cursor[r - 1] : 0;
    int end = cursor[r];
    float4 a0 = zero4(), a1 = zero4();
    const int4* yi = (const int4*)y;
    for (int base = start; base < end; base += 16) {
        int e0 = base + g, e1 = base + 8 + g;
        float m0 = (e0 < end) ? 1.f : 0.f;
        float m1 = (e1 < end) ? 1.f : 0.f;
        int i0 = (e0 < end) ? csr[e0] : 0;
        int i1 = (e1 < end) ? csr[e1] : 0;
        if (c < 5) {
            int4 v0 = yi[(size_t)i0 * 5 + c];
            int4 v1 = yi[(size_t)i1 * 5 + c];
            acc_h8m(a0, a1, v0, m0);
            acc_h8m(a0, a1, v1, m1);
        }
    }
#pragma unroll
    for (int m = 8; m <= 32; m <<= 1) {
        float4 t0, t1;
        t0.x = __shfl_xor(a0.x, m); t0.y = __shfl_xor(a0.y, m);
        t0.z = __shfl_xor(a0.z, m); t0.w = __shfl_xor(a0.w, m);
        t1.x = __shfl_xor(a1.x, m); t1.y = __shfl_xor(a1.y, m);
        t1.z = __shfl_xor(a1.z, m); t1.w = __shfl_xor(a1.w, m);
        a0.x += t0.x; a0.y += t0.y; a0.z += t0.z; a0.w += t0.w;
        a1.x += t1.x; a1.y += t1.y; a1.z += t1.z; a1.w += t1.w;
    }
    if (g == 0 && c < 5) {
        float s = nd[r];
        float4 b20 = ((const float4*)b2)[c * 2 + 0];
        float4 b21 = ((const float4*)b2)[c * 2 + 1];
        float4 o0, o1;
        o0.x = fmaf(a0.x, s, b20.x); o0.y = fmaf(a0.y, s, b20.y);
        o0.z = fmaf(a0.z, s, b20.z); o0.w = fmaf(a0.w, s, b20.w);
        o1.x = fmaf(a1.x, s, b21.x); o1.y = fmaf(a1.y, s, b21.y);
        o1.z = fmaf(a1.z, s, b21.z); o1.w = fmaf(a1.w, s, b21.w);
        float* op = out + (size_t)r * NCLS + c * 8;
        *(float4*)(op + 0) = o0;
        *(float4*)(op + 4) = o1;
    }
}

extern "C" void kernel_launch(void* const* d_in, const int* in_sizes, int n_in,
                              void* d_out, int out_size, void* d_ws, size_t ws_size,
                              hipStream_t stream) {
    const float* x  = (const float*)d_in[0];
    const int* src  = (const int*)d_in[1];
    const int* dst  = (const int*)d_in[2];
    const float* W0 = (const float*)d_in[3];
    const float* b0 = (const float*)d_in[4];
    const float* W1 = (const float*)d_in[5];
    const float* b1 = (const float*)d_in[6];
    const float* W2 = (const float*)d_in[7];
    const float* b2 = (const float*)d_in[8];
    float* out = (float*)d_out;

    int N = in_sizes[0] / IN_DIM;
    int E = in_sizes[1];

    float* base = (float*)d_ws;
    float* ns   = base;                       // N
    float* ndn  = base + (size_t)N;           // N
    int* dsg    = (int*)(base + 2 * (size_t)N);
    int* ddg    = (int*)(base + 3 * (size_t)N);
    int* cursor = (int*)(base + 4 * (size_t)N);
    int* bsums  = (int*)(base + 5 * (size_t)N);          // 1024
    int* csr    = (int*)(base + 5 * (size_t)N + 1024);   // E
    __half* bufA = (__half*)(csr + (size_t)E);           // N x 128 halves (xh / agg1)
    __half* bufB = bufA + (size_t)N * 128;               // N x 128 halves (h0)
    __half* bufC = bufB + (size_t)N * 128;               // N x 128 halves (agg0 / h1)
    __half* yh   = bufC + (size_t)N * 128;               // N x 40 halves

    int nb = (N + 1023) / 1024;

    (void)hipMemsetAsync(dsg, 0, 2 * (size_t)N * sizeof(int), stream);
    deg_kernel<<<(E + 255) / 256, 256, 0, stream>>>(src, dst, dsg, ddg, E);
    norm_kernel<<<(N + 255) / 256, 256, 0, stream>>>(dsg, ddg, ns, ndn, N);

    scan_partial<<<nb, 256, 0, stream>>>(ddg, bsums, N);
    scan_bsums<<<1, 128, 0, stream>>>(bsums, nb);
    scan_final<<<nb, 256, 0, stream>>>(ddg, bsums, cursor, N);
    fill_csr<<<(E + 255) / 256, 256, 0, stream>>>(src, dst, cursor, csr, E);

    // bufA = fp16(x * ns)
    prescale_kernel<<<(N * 16 + 255) / 256, 256, 0, stream>>>(x, ns, bufA, N);

    int nrb = (N + 127) / 128;
    int g64 = (N + 63) / 64;

    // layer 0: agg0 = spmm(bufA) -> bufC ; h0 = relu(agg0*nd @ W0 + b0)*ns -> bufB
    spmm16<<<nrb * 8, 256, 0, stream>>>(bufA, csr, cursor, bufC, N);
    gemm128h<1><<<g64, 256, 0, stream>>>(bufC, ndn, ns, W0, b0, bufB, N);

    // layer 1: agg1 = spmm(bufB) -> bufA ; h1 = relu(agg1*nd @ W1 + b1) -> bufC
    spmm16<<<nrb * 8, 256, 0, stream>>>(bufB, csr, cursor, bufA, N);
    gemm128h<0><<<g64, 256, 0, stream>>>(bufA, ndn, ns, W1, b1, bufC, N);

    // layer 2: yh = (h1 @ W2) * ns ; out = gather40(yh)*nd + b2
    gemm40_kernel<<<(N + 31) / 32, 256, 0, stream>>>(bufC, W2, ns, yh, N);
    gather40_finish<<<(N + 3) / 4, 256, 0, stream>>>(yh, csr, cursor, ndn, b2, out, N);
}

// Round 11
// 739.972 us; speedup vs baseline: 1.2338x; 1.2338x over previous
//
#include <hip/hip_runtime.h>
#include <hip/hip_fp16.h>

#define IN_DIM 128
#define NCLS 40
#define AS_STRIDE 136   // halves; 272 B row stride

// ---------------- degree / norm ----------------

__global__ __launch_bounds__(256) void deg_kernel(const int* __restrict__ src, const int* __restrict__ dst,
                                                  int* __restrict__ ds, int* __restrict__ dd, int E) {
    int e = blockIdx.x * 256 + threadIdx.x;
    if (e < E) {
        atomicAdd(&ds[src[e]], 1);
        atomicAdd(&dd[dst[e]], 1);
    }
}

__global__ __launch_bounds__(256) void norm_kernel(const int* __restrict__ ds, const int* __restrict__ dd,
                                                   float* __restrict__ ns, float* __restrict__ nd, int N) {
    int i = blockIdx.x * 256 + threadIdx.x;
    if (i < N) {
        ns[i] = ds[i] > 0 ? rsqrtf((float)ds[i]) : 0.f;
        nd[i] = dd[i] > 0 ? rsqrtf((float)dd[i]) : 0.f;
    }
}

// ---------------- exclusive scan of in-degrees -> row_ptr ----------------

__global__ __launch_bounds__(256) void scan_partial(const int* __restrict__ dd, int* __restrict__ bsums, int N) {
    __shared__ int sd[256];
    int t = threadIdx.x;
    int base = blockIdx.x * 1024 + t * 4;
    int s = 0;
#pragma unroll
    for (int k = 0; k < 4; ++k) { int i = base + k; if (i < N) s += dd[i]; }
    sd[t] = s;
    __syncthreads();
    for (int off = 128; off > 0; off >>= 1) {
        if (t < off) sd[t] += sd[t + off];
        __syncthreads();
    }
    if (t == 0) bsums[blockIdx.x] = sd[0];
}

__global__ __launch_bounds__(128) void scan_bsums(int* __restrict__ bsums, int nb) {
    __shared__ int sd[128];
    __shared__ int carry_s;
    int t = threadIdx.x;
    if (t == 0) carry_s = 0;
    __syncthreads();
    for (int base = 0; base < nb; base += 128) {
        int i = base + t;
        int orig = (i < nb) ? bsums[i] : 0;
        sd[t] = orig;
        __syncthreads();
        for (int off = 1; off < 128; off <<= 1) {
            int u = (t >= off) ? sd[t - off] : 0;
            __syncthreads();
            sd[t] += u;
            __syncthreads();
        }
        int carry = carry_s;
        if (i < nb) bsums[i] = carry + sd[t] - orig;   // exclusive
        __syncthreads();
        if (t == 127) carry_s = carry + sd[127];
        __syncthreads();
    }
}

__global__ __launch_bounds__(256) void scan_final(const int* __restrict__ dd, const int* __restrict__ bsums,
                                                  int* __restrict__ cursor, int N) {
    __shared__ int sd[256];
    int t = threadIdx.x;
    int base = blockIdx.x * 1024 + t * 4;
    int v[4]; int s = 0;
#pragma unroll
    for (int k = 0; k < 4; ++k) { int i = base + k; v[k] = (i < N) ? dd[i] : 0; s += v[k]; }
    sd[t] = s;
    __syncthreads();
    for (int off = 1; off < 256; off <<= 1) {
        int u = (t >= off) ? sd[t - off] : 0;
        __syncthreads();
        sd[t] += u;
        __syncthreads();
    }
    int excl = sd[t] - s + bsums[blockIdx.x];
#pragma unroll
    for (int k = 0; k < 4; ++k) {
        int i = base + k;
        if (i < N) cursor[i] = excl;
        excl += v[k];
    }
}

__global__ __launch_bounds__(256) void fill_csr(const int* __restrict__ src, const int* __restrict__ dst,
                                                int* __restrict__ cursor, int* __restrict__ csr, int E) {
    int e = blockIdx.x * 256 + threadIdx.x;
    if (e < E) {
        int slot = atomicAdd(&cursor[dst[e]], 1);
        csr[slot] = src[e];
    }
}

// ---------------- helpers ----------------

__device__ __forceinline__ float4 zero4() { return make_float4(0.f, 0.f, 0.f, 0.f); }

__device__ __forceinline__ void fma4(float4& acc, float s, const float4& wv) {
    acc.x = fmaf(s, wv.x, acc.x);
    acc.y = fmaf(s, wv.y, acc.y);
    acc.z = fmaf(s, wv.z, acc.z);
    acc.w = fmaf(s, wv.w, acc.w);
}

__device__ __forceinline__ void add_h8(float4& a0, float4& a1, const int4& v) {
    const __half2* h = (const __half2*)&v;
    float2 f0 = __half22float2(h[0]);
    float2 f1 = __half22float2(h[1]);
    float2 f2 = __half22float2(h[2]);
    float2 f3 = __half22float2(h[3]);
    a0.x += f0.x; a0.y += f0.y; a0.z += f1.x; a0.w += f1.y;
    a1.x += f2.x; a1.y += f2.y; a1.z += f3.x; a1.w += f3.y;
}

__device__ __forceinline__ int4 pack_h8(const float4& o0, const float4& o1) {
    int4 p;
    __half2* ph = (__half2*)&p;
    ph[0] = __float22half2_rn(make_float2(o0.x, o0.y));
    ph[1] = __float22half2_rn(make_float2(o0.z, o0.w));
    ph[2] = __float22half2_rn(make_float2(o1.x, o1.y));
    ph[3] = __float22half2_rn(make_float2(o1.z, o1.w));
    return p;
}

// ---------------- prescale into slabs: slab s holds halves [16s,16s+16) of every row ----------
// slab layout (int4 units): base + s*2N + n*2 + h,  s in [0,8), h in [0,2)

__global__ __launch_bounds__(256) void prescale_kernel(const float* __restrict__ x, const float* __restrict__ ns,
                                                       __half* __restrict__ xs, int N) {
    int tid = blockIdx.x * 256 + threadIdx.x;     // over 16N int4s, slab-major (coalesced writes)
    if (tid >= N * 16) return;
    int s = tid / (2 * N);
    int rem = tid - s * 2 * N;
    int n = rem >> 1;
    int h = rem & 1;
    float sc = ns[n];
    const float4* xp = (const float4*)x + (size_t)n * 32 + (s * 2 + h) * 2;
    float4 v0 = xp[0], v1 = xp[1];
    v0.x *= sc; v0.y *= sc; v0.z *= sc; v0.w *= sc;
    v1.x *= sc; v1.y *= sc; v1.z *= sc; v1.w *= sc;
    ((int4*)xs)[tid] = pack_h8(v0, v1);
}

// ---------------- slab SpMM: agg_slab[s][r] = sum_{src in N(r)} x_slab[s][src] ----------------
// grid = nrb*8; slice = bid&7 -> one 3.2 MB slab, pinned to one XCD (bid%8 round-robin).
// 128 rows/block; thread = (row, 16B half). All gather loads hit the slab in L2.

__global__ __launch_bounds__(256) void spmm16s(const __half* __restrict__ xs, const int* __restrict__ csr,
                                               const int* __restrict__ cursor, __half* __restrict__ as_, int N) {
    int bid = blockIdx.x;
    int slice = bid & 7;
    int rb = bid >> 3;
    int r = rb * 128 + (threadIdx.x >> 1);
    if (r >= N) return;
    int h = threadIdx.x & 1;
    const int4* xi = (const int4*)xs + (size_t)slice * N * 2;
    int start = r ? cursor[r - 1] : 0;
    int end = cursor[r];
    float4 a0 = zero4(), a1 = zero4();
    int e = start;
    for (; e + 4 <= end; e += 4) {
        int i0 = csr[e + 0], i1 = csr[e + 1], i2 = csr[e + 2], i3 = csr[e + 3];
        int4 v0 = xi[(size_t)i0 * 2 + h];
        int4 v1 = xi[(size_t)i1 * 2 + h];
        int4 v2 = xi[(size_t)i2 * 2 + h];
        int4 v3 = xi[(size_t)i3 * 2 + h];
        add_h8(a0, a1, v0); add_h8(a0, a1, v1);
        add_h8(a0, a1, v2); add_h8(a0, a1, v3);
    }
    for (; e < end; ++e) {
        int4 v0 = xi[(size_t)csr[e] * 2 + h];
        add_h8(a0, a1, v0);
    }
    ((int4*)as_)[(size_t)slice * N * 2 + (size_t)r * 2 + h] = pack_h8(a0, a1);
}

// ---------------- GEMM 128(fp16 slab agg) -> 128, epilogue acc*nd+bias, relu, (*ns) -> slabs --

template<int SCALE_NS>
__global__ __launch_bounds__(256, 6) void gemm128h(const __half* __restrict__ agg, const float* __restrict__ nd,
                                                   const float* __restrict__ ns, const float* __restrict__ W,
                                                   const float* __restrict__ bias, __half* __restrict__ out, int N) {
    __shared__ __half As[64 * AS_STRIDE];
    int t = threadIdx.x;
    int row0 = blockIdx.x * 64;

    // stage 64 rows from 8 slabs (coalesced within slab)
#pragma unroll
    for (int i = 0; i < 4; ++i) {
        int idx = t + 256 * i;          // 0..1023
        int s = idx >> 7;               // 0..7
        int rem = idx & 127;
        int r = rem >> 1;               // 0..63
        int h = rem & 1;
        int gr = row0 + r;
        int4 v = make_int4(0, 0, 0, 0);
        if (gr < N) v = ((const int4*)agg)[(size_t)s * N * 2 + (size_t)gr * 2 + h];
        *(int4*)&As[r * AS_STRIDE + (s * 2 + h) * 8] = v;
    }
    __syncthreads();

    int rg = t >> 4;
    int cgp = t & 15;
    int rbase = rg * 4;
    const float4* Wg = (const float4*)W;
    float4 acc[4][2];
#pragma unroll
    for (int m = 0; m < 4; ++m) { acc[m][0] = zero4(); acc[m][1] = zero4(); }
#pragma unroll 2
    for (int k4 = 0; k4 < 32; ++k4) {
        int k0 = k4 * 4;
        float4 a[4];
#pragma unroll
        for (int m = 0; m < 4; ++m) {
            uint2 raw = *(const uint2*)&As[(rbase + m) * AS_STRIDE + k0];
            const __half2* hp = (const __half2*)&raw;
            float2 f0 = __half22float2(hp[0]);
            float2 f1 = __half22float2(hp[1]);
            a[m] = make_float4(f0.x, f0.y, f1.x, f1.y);
        }
        float4 w[4][2];
#pragma unroll
        for (int j = 0; j < 4; ++j) {
            w[j][0] = Wg[(k0 + j) * 32 + cgp * 2 + 0];
            w[j][1] = Wg[(k0 + j) * 32 + cgp * 2 + 1];
        }
#pragma unroll
        for (int m = 0; m < 4; ++m) {
            fma4(acc[m][0], a[m].x, w[0][0]); fma4(acc[m][1], a[m].x, w[0][1]);
            fma4(acc[m][0], a[m].y, w[1][0]); fma4(acc[m][1], a[m].y, w[1][1]);
            fma4(acc[m][0], a[m].z, w[2][0]); fma4(acc[m][1], a[m].z, w[2][1]);
            fma4(acc[m][0], a[m].w, w[3][0]); fma4(acc[m][1], a[m].w, w[3][1]);
        }
    }

    float4 bb0 = ((const float4*)bias)[cgp * 2 + 0];
    float4 bb1 = ((const float4*)bias)[cgp * 2 + 1];
    int os = cgp >> 1, oh = cgp & 1;
#pragma unroll
    for (int m = 0; m < 4; ++m) {
        int gr = row0 + rbase + m;
        if (gr < N) {
            float ndr = nd[gr];
            float4 o0, o1;
            o0.x = fmaxf(fmaf(acc[m][0].x, ndr, bb0.x), 0.f);
            o0.y = fmaxf(fmaf(acc[m][0].y, ndr, bb0.y), 0.f);
            o0.z = fmaxf(fmaf(acc[m][0].z, ndr, bb0.z), 0.f);
            o0.w = fmaxf(fmaf(acc[m][0].w, ndr, bb0.w), 0.f);
            o1.x = fmaxf(fmaf(acc[m][1].x, ndr, bb1.x), 0.f);
            o1.y = fmaxf(fmaf(acc[m][1].y, ndr, bb1.y), 0.f);
            o1.z = fmaxf(fmaf(acc[m][1].z, ndr, bb1.z), 0.f);
            o1.w = fmaxf(fmaf(acc[m][1].w, ndr, bb1.w), 0.f);
            if (SCALE_NS) {
                float s = ns[gr];
                o0.x *= s; o0.y *= s; o0.z *= s; o0.w *= s;
                o1.x *= s; o1.y *= s; o1.z *= s; o1.w *= s;
            }
            ((int4*)out)[(size_t)os * N * 2 + (size_t)gr * 2 + oh] = pack_h8(o0, o1);
        }
    }
}

// ---------------- GEMM 128(slab fp16) -> 40, *ns, output 5 slabs of int4 (8 halves) ----------

__global__ __launch_bounds__(256) void gemm40_kernel(const __half* __restrict__ A, const float* __restrict__ W,
                                                     const float* __restrict__ ns, __half* __restrict__ y, int N) {
    __shared__ float Ws[128 * NCLS];   // 20 KB
    __shared__ float As[32 * 132];     // 16.5 KB
    __shared__ __half ys[32][40];      // 2.5 KB repack buffer
    int t = threadIdx.x;
    int row0 = blockIdx.x * 32;

#pragma unroll
    for (int i = 0; i < 5; ++i) {
        int idx = t + 256 * i;
        ((float4*)Ws)[idx] = ((const float4*)W)[idx];
    }
    // stage 32 rows from 8 slabs
#pragma unroll
    for (int i = 0; i < 2; ++i) {
        int idx = t + 256 * i;        // 0..511
        int s = idx >> 6;             // 0..7
        int rem = idx & 63;
        int r = rem >> 1;             // 0..31
        int h = rem & 1;
        int gr = row0 + r;
        int4 v = make_int4(0, 0, 0, 0);
        if (gr < N) v = ((const int4*)A)[(size_t)s * N * 2 + (size_t)gr * 2 + h];
        const __half2* hh = (const __half2*)&v;
        float2 f0 = __half22float2(hh[0]);
        float2 f1 = __half22float2(hh[1]);
        float2 f2 = __half22float2(hh[2]);
        float2 f3 = __half22float2(hh[3]);
        float* dp = &As[r * 132 + (s * 2 + h) * 8];
        dp[0] = f0.x; dp[1] = f0.y; dp[2] = f1.x; dp[3] = f1.y;
        dp[4] = f2.x; dp[5] = f2.y; dp[6] = f3.x; dp[7] = f3.y;
    }
    __syncthreads();

    int row = t >> 3;
    int cg = t & 7;
    float acc[5] = {0.f, 0.f, 0.f, 0.f, 0.f};
#pragma unroll 2
    for (int k4 = 0; k4 < 32; ++k4) {
        float4 a = *(const float4*)&As[row * 132 + k4 * 4];
#pragma unroll
        for (int j = 0; j < 4; ++j) {
            float av = (j == 0) ? a.x : (j == 1) ? a.y : (j == 2) ? a.z : a.w;
            const float* wp = &Ws[(k4 * 4 + j) * NCLS + cg * 5];
            acc[0] = fmaf(av, wp[0], acc[0]);
            acc[1] = fmaf(av, wp[1], acc[1]);
            acc[2] = fmaf(av, wp[2], acc[2]);
            acc[3] = fmaf(av, wp[3], acc[3]);
            acc[4] = fmaf(av, wp[4], acc[4]);
        }
    }
    {
        int gr = row0 + row;
        float s = (gr < N) ? ns[gr] : 0.f;
        __half* yp = &ys[row][cg * 5];
        yp[0] = __float2half_rn(acc[0] * s);
        yp[1] = __float2half_rn(acc[1] * s);
        yp[2] = __float2half_rn(acc[2] * s);
        yp[3] = __float2half_rn(acc[3] * s);
        yp[4] = __float2half_rn(acc[4] * s);
    }
    __syncthreads();
    // repack: 5 slabs of int4 per row
    if (t < 160) {
        int s = t >> 5;      // 0..4
        int r = t & 31;
        int gr = row0 + r;
        if (gr < N) ((int4*)y)[(size_t)s * N + gr] = *(const int4*)&ys[r][s * 8];
    }
}

// ---------------- slab gather 40-d + *nd + b2 -> out (fp32) ----------------
// grid = nrb256*5; slice = bid%5 (1.6 MB slab); 1 thread per row.

__global__ __launch_bounds__(256) void gather40f(const __half* __restrict__ y, const int* __restrict__ csr,
                                                 const int* __restrict__ cursor, const float* __restrict__ nd,
                                                 const float* __restrict__ b2, float* __restrict__ out, int N) {
    int bid = blockIdx.x;
    int slice = bid % 5;
    int rb = bid / 5;
    int r = rb * 256 + threadIdx.x;
    if (r >= N) return;
    const int4* ys = (const int4*)y + (size_t)slice * N;
    int start = r ? cursor[r - 1] : 0;
    int end = cursor[r];
    float4 a0 = zero4(), a1 = zero4();
    int e = start;
    for (; e + 4 <= end; e += 4) {
        int i0 = csr[e + 0], i1 = csr[e + 1], i2 = csr[e + 2], i3 = csr[e + 3];
        int4 v0 = ys[i0];
        int4 v1 = ys[i1];
        int4 v2 = ys[i2];
        int4 v3 = ys[i3];
        add_h8(a0, a1, v0); add_h8(a0, a1, v1);
        add_h8(a0, a1, v2); add_h8(a0, a1, v3);
    }
    for (; e < end; ++e) {
        int4 v0 = ys[csr[e]];
        add_h8(a0, a1, v0);
    }
    float s = nd[r];
    const float* bp = b2 + slice * 8;
    float4 o0, o1;
    o0.x = fmaf(a0.x, s, bp[0]); o0.y = fmaf(a0.y, s, bp[1]);
    o0.z = fmaf(a0.z, s, bp[2]); o0.w = fmaf(a0.w, s, bp[3]);
    o1.x = fmaf(a1.x, s, bp[4]); o1.y = fmaf(a1.y, s, bp[5]);
    o1.z = fmaf(a1.z, s, bp[6]); o1.w = fmaf(a1.w, s, bp[7]);
    float* op = out + (size_t)r * NCLS + slice * 8;
    *(float4*)(op + 0) = o0;
    *(float4*)(op + 4) = o1;
}

extern "C" void kernel_launch(void* const* d_in, const int* in_sizes, int n_in,
                              void* d_out, int out_size, void* d_ws, size_t ws_size,
                              hipStream_t stream) {
    const float* x  = (const float*)d_in[0];
    const int* src  = (const int*)d_in[1];
    const int* dst  = (const int*)d_in[2];
    const float* W0 = (const float*)d_in[3];
    const float* b0 = (const float*)d_in[4];
    const float* W1 = (const float*)d_in[5];
    const float* b1 = (const float*)d_in[6];
    const float* W2 = (const float*)d_in[7];
    const float* b2 = (const float*)d_in[8];
    float* out = (float*)d_out;

    int N = in_sizes[0] / IN_DIM;
    int E = in_sizes[1];

    float* base = (float*)d_ws;
    float* ns   = base;                       // N
    float* ndn  = base + (size_t)N;           // N
    int* dsg    = (int*)(base + 2 * (size_t)N);
    int* ddg    = (int*)(base + 3 * (size_t)N);
    int* cursor = (int*)(base + 4 * (size_t)N);
    int* bsums  = (int*)(base + 5 * (size_t)N);          // 1024
    int* csr    = (int*)(base + 5 * (size_t)N + 1024);   // E
    __half* B0  = (__half*)(csr + (size_t)E);            // N x 128 halves (slabs)
    __half* B1  = B0 + (size_t)N * 128;                  // N x 128 halves (slabs)
    __half* B2  = B1 + (size_t)N * 128;                  // N x 128 halves (slabs)
    __half* yh  = B2 + (size_t)N * 128;                  // 5 slabs x N int4 = N x 80 halves

    int nb = (N + 1023) / 1024;

    (void)hipMemsetAsync(dsg, 0, 2 * (size_t)N * sizeof(int), stream);
    deg_kernel<<<(E + 255) / 256, 256, 0, stream>>>(src, dst, dsg, ddg, E);
    norm_kernel<<<(N + 255) / 256, 256, 0, stream>>>(dsg, ddg, ns, ndn, N);

    scan_partial<<<nb, 256, 0, stream>>>(ddg, bsums, N);
    scan_bsums<<<1, 128, 0, stream>>>(bsums, nb);
    scan_final<<<nb, 256, 0, stream>>>(ddg, bsums, cursor, N);
    fill_csr<<<(E + 255) / 256, 256, 0, stream>>>(src, dst, cursor, csr, E);

    // B0 = slabbed fp16(x * ns)
    prescale_kernel<<<(N * 16 + 255) / 256, 256, 0, stream>>>(x, ns, B0, N);

    int nrb = (N + 127) / 128;
    int g64 = (N + 63) / 64;
    int nrb256 = (N + 255) / 256;

    // layer 0: B1 = spmm(B0) ; B2 = relu(B1*nd @ W0 + b0)*ns   (all slabbed)
    spmm16s<<<nrb * 8, 256, 0, stream>>>(B0, csr, cursor, B1, N);
    gemm128h<1><<<g64, 256, 0, stream>>>(B1, ndn, ns, W0, b0, B2, N);

    // layer 1: B1 = spmm(B2) ; B0 = relu(B1*nd @ W1 + b1)
    spmm16s<<<nrb * 8, 256, 0, stream>>>(B2, csr, cursor, B1, N);
    gemm128h<0><<<g64, 256, 0, stream>>>(B1, ndn, ns, W1, b1, B0, N);

    // layer 2: yh = (B0 @ W2)*ns (5 slabs) ; out = gather40(yh)*nd + b2
    gemm40_kernel<<<(N + 31) / 32, 256, 0, stream>>>(B0, W2, ns, yh, N);
    gather40f<<<nrb256 * 5, 256, 0, stream>>>(yh, csr, cursor, ndn, b2, out, N);
}

// Round 12
// 694.047 us; speedup vs baseline: 1.3154x; 1.0662x over previous
//
#include <hip/hip_runtime.h>
#include <hip/hip_fp16.h>

#define IN_DIM 128
#define NCLS 40
#define AS_STRIDE 136   // halves; 272 B row stride
#define DEG_BLKS 96     // blocks per slice for sliced atomic kernels

// ---------------- degree (8-way node-range sliced: atomics stay XCD-local) ----------------

__global__ __launch_bounds__(256) void deg_sliced(const int* __restrict__ src, const int* __restrict__ dst,
                                                  int* __restrict__ ds, int* __restrict__ dd, int E, int N) {
    int bid = blockIdx.x;
    int slice = bid & 7;
    int sb = bid >> 3;
    int chunk = (N + 7) >> 3;
    int lo = slice * chunk;
    int hi = min(lo + chunk, N);
    int stride = DEG_BLKS * 256;
    for (int e = sb * 256 + threadIdx.x; e < E; e += stride) {
        int sv = src[e];
        if (sv >= lo && sv < hi) atomicAdd(&ds[sv], 1);
        int dv = dst[e];
        if (dv >= lo && dv < hi) atomicAdd(&dd[dv], 1);
    }
}

__global__ __launch_bounds__(256) void norm_kernel(const int* __restrict__ ds, const int* __restrict__ dd,
                                                   float* __restrict__ ns, float* __restrict__ nd, int N) {
    int i = blockIdx.x * 256 + threadIdx.x;
    if (i < N) {
        ns[i] = ds[i] > 0 ? rsqrtf((float)ds[i]) : 0.f;
        nd[i] = dd[i] > 0 ? rsqrtf((float)dd[i]) : 0.f;
    }
}

// ---------------- exclusive scan of in-degrees -> row_ptr ----------------

__global__ __launch_bounds__(256) void scan_partial(const int* __restrict__ dd, int* __restrict__ bsums, int N) {
    __shared__ int sd[256];
    int t = threadIdx.x;
    int base = blockIdx.x * 1024 + t * 4;
    int s = 0;
#pragma unroll
    for (int k = 0; k < 4; ++k) { int i = base + k; if (i < N) s += dd[i]; }
    sd[t] = s;
    __syncthreads();
    for (int off = 128; off > 0; off >>= 1) {
        if (t < off) sd[t] += sd[t + off];
        __syncthreads();
    }
    if (t == 0) bsums[blockIdx.x] = sd[0];
}

__global__ __launch_bounds__(128) void scan_bsums(int* __restrict__ bsums, int nb) {
    __shared__ int sd[128];
    __shared__ int carry_s;
    int t = threadIdx.x;
    if (t == 0) carry_s = 0;
    __syncthreads();
    for (int base = 0; base < nb; base += 128) {
        int i = base + t;
        int orig = (i < nb) ? bsums[i] : 0;
        sd[t] = orig;
        __syncthreads();
        for (int off = 1; off < 128; off <<= 1) {
            int u = (t >= off) ? sd[t - off] : 0;
            __syncthreads();
            sd[t] += u;
            __syncthreads();
        }
        int carry = carry_s;
        if (i < nb) bsums[i] = carry + sd[t] - orig;   // exclusive
        __syncthreads();
        if (t == 127) carry_s = carry + sd[127];
        __syncthreads();
    }
}

__global__ __launch_bounds__(256) void scan_final(const int* __restrict__ dd, const int* __restrict__ bsums,
                                                  int* __restrict__ cursor, int N) {
    __shared__ int sd[256];
    int t = threadIdx.x;
    int base = blockIdx.x * 1024 + t * 4;
    int v[4]; int s = 0;
#pragma unroll
    for (int k = 0; k < 4; ++k) { int i = base + k; v[k] = (i < N) ? dd[i] : 0; s += v[k]; }
    sd[t] = s;
    __syncthreads();
    for (int off = 1; off < 256; off <<= 1) {
        int u = (t >= off) ? sd[t - off] : 0;
        __syncthreads();
        sd[t] += u;
        __syncthreads();
    }
    int excl = sd[t] - s + bsums[blockIdx.x];
#pragma unroll
    for (int k = 0; k < 4; ++k) {
        int i = base + k;
        if (i < N) cursor[i] = excl;
        excl += v[k];
    }
}

// ---------------- CSR fill (8-way dst-range sliced: cursor atomics + csr writes XCD-local) ----

__global__ __launch_bounds__(256) void fill_csr_sliced(const int* __restrict__ src, const int* __restrict__ dst,
                                                       int* __restrict__ cursor, int* __restrict__ csr,
                                                       int E, int N) {
    int bid = blockIdx.x;
    int slice = bid & 7;
    int sb = bid >> 3;
    int chunk = (N + 7) >> 3;
    int lo = slice * chunk;
    int hi = min(lo + chunk, N);
    int stride = DEG_BLKS * 256;
    for (int e = sb * 256 + threadIdx.x; e < E; e += stride) {
        int dv = dst[e];
        if (dv >= lo && dv < hi) {
            int slot = atomicAdd(&cursor[dv], 1);
            csr[slot] = src[e];
        }
    }
}

// ---------------- helpers ----------------

__device__ __forceinline__ float4 zero4() { return make_float4(0.f, 0.f, 0.f, 0.f); }

__device__ __forceinline__ void fma4(float4& acc, float s, const float4& wv) {
    acc.x = fmaf(s, wv.x, acc.x);
    acc.y = fmaf(s, wv.y, acc.y);
    acc.z = fmaf(s, wv.z, acc.z);
    acc.w = fmaf(s, wv.w, acc.w);
}

__device__ __forceinline__ void add_h8(float4& a0, float4& a1, const int4& v) {
    const __half2* h = (const __half2*)&v;
    float2 f0 = __half22float2(h[0]);
    float2 f1 = __half22float2(h[1]);
    float2 f2 = __half22float2(h[2]);
    float2 f3 = __half22float2(h[3]);
    a0.x += f0.x; a0.y += f0.y; a0.z += f1.x; a0.w += f1.y;
    a1.x += f2.x; a1.y += f2.y; a1.z += f3.x; a1.w += f3.y;
}

__device__ __forceinline__ int4 pack_h8(const float4& o0, const float4& o1) {
    int4 p;
    __half2* ph = (__half2*)&p;
    ph[0] = __float22half2_rn(make_float2(o0.x, o0.y));
    ph[1] = __float22half2_rn(make_float2(o0.z, o0.w));
    ph[2] = __float22half2_rn(make_float2(o1.x, o1.y));
    ph[3] = __float22half2_rn(make_float2(o1.z, o1.w));
    return p;
}

// ---------------- prescale into slabs: slab s holds halves [16s,16s+16) of every row ----------

__global__ __launch_bounds__(256) void prescale_kernel(const float* __restrict__ x, const float* __restrict__ ns,
                                                       __half* __restrict__ xs, int N) {
    int tid = blockIdx.x * 256 + threadIdx.x;     // over 16N int4s, slab-major
    if (tid >= N * 16) return;
    int s = tid / (2 * N);
    int rem = tid - s * 2 * N;
    int n = rem >> 1;
    int h = rem & 1;
    float sc = ns[n];
    const float4* xp = (const float4*)x + (size_t)n * 32 + (s * 2 + h) * 2;
    float4 v0 = xp[0], v1 = xp[1];
    v0.x *= sc; v0.y *= sc; v0.z *= sc; v0.w *= sc;
    v1.x *= sc; v1.y *= sc; v1.z *= sc; v1.w *= sc;
    ((int4*)xs)[tid] = pack_h8(v0, v1);
}

// ---------------- slab SpMM: agg_slab[s][r] = sum_{src in N(r)} x_slab[s][src] ----------------

__global__ __launch_bounds__(256) void spmm16s(const __half* __restrict__ xs, const int* __restrict__ csr,
                                               const int* __restrict__ cursor, __half* __restrict__ as_, int N) {
    int bid = blockIdx.x;
    int slice = bid & 7;
    int rb = bid >> 3;
    int r = rb * 128 + (threadIdx.x >> 1);
    if (r >= N) return;
    int h = threadIdx.x & 1;
    const int4* xi = (const int4*)xs + (size_t)slice * N * 2;
    int start = r ? cursor[r - 1] : 0;
    int end = cursor[r];
    float4 a0 = zero4(), a1 = zero4();
    int e = start;
    for (; e + 4 <= end; e += 4) {
        int i0 = csr[e + 0], i1 = csr[e + 1], i2 = csr[e + 2], i3 = csr[e + 3];
        int4 v0 = xi[(size_t)i0 * 2 + h];
        int4 v1 = xi[(size_t)i1 * 2 + h];
        int4 v2 = xi[(size_t)i2 * 2 + h];
        int4 v3 = xi[(size_t)i3 * 2 + h];
        add_h8(a0, a1, v0); add_h8(a0, a1, v1);
        add_h8(a0, a1, v2); add_h8(a0, a1, v3);
    }
    for (; e < end; ++e) {
        int4 v0 = xi[(size_t)csr[e] * 2 + h];
        add_h8(a0, a1, v0);
    }
    ((int4*)as_)[(size_t)slice * N * 2 + (size_t)r * 2 + h] = pack_h8(a0, a1);
}

// ---------------- GEMM 128(fp16 slab agg) -> 128, epilogue acc*nd+bias, relu, (*ns) -> slabs --

template<int SCALE_NS>
__global__ __launch_bounds__(256, 6) void gemm128h(const __half* __restrict__ agg, const float* __restrict__ nd,
                                                   const float* __restrict__ ns, const float* __restrict__ W,
                                                   const float* __restrict__ bias, __half* __restrict__ out, int N) {
    __shared__ __half As[64 * AS_STRIDE];
    int t = threadIdx.x;
    int row0 = blockIdx.x * 64;

#pragma unroll
    for (int i = 0; i < 4; ++i) {
        int idx = t + 256 * i;          // 0..1023
        int s = idx >> 7;
        int rem = idx & 127;
        int r = rem >> 1;
        int h = rem & 1;
        int gr = row0 + r;
        int4 v = make_int4(0, 0, 0, 0);
        if (gr < N) v = ((const int4*)agg)[(size_t)s * N * 2 + (size_t)gr * 2 + h];
        *(int4*)&As[r * AS_STRIDE + (s * 2 + h) * 8] = v;
    }
    __syncthreads();

    int rg = t >> 4;
    int cgp = t & 15;
    int rbase = rg * 4;
    const float4* Wg = (const float4*)W;
    float4 acc[4][2];
#pragma unroll
    for (int m = 0; m < 4; ++m) { acc[m][0] = zero4(); acc[m][1] = zero4(); }
#pragma unroll 2
    for (int k4 = 0; k4 < 32; ++k4) {
        int k0 = k4 * 4;
        float4 a[4];
#pragma unroll
        for (int m = 0; m < 4; ++m) {
            uint2 raw = *(const uint2*)&As[(rbase + m) * AS_STRIDE + k0];
            const __half2* hp = (const __half2*)&raw;
            float2 f0 = __half22float2(hp[0]);
            float2 f1 = __half22float2(hp[1]);
            a[m] = make_float4(f0.x, f0.y, f1.x, f1.y);
        }
        float4 w[4][2];
#pragma unroll
        for (int j = 0; j < 4; ++j) {
            w[j][0] = Wg[(k0 + j) * 32 + cgp * 2 + 0];
            w[j][1] = Wg[(k0 + j) * 32 + cgp * 2 + 1];
        }
#pragma unroll
        for (int m = 0; m < 4; ++m) {
            fma4(acc[m][0], a[m].x, w[0][0]); fma4(acc[m][1], a[m].x, w[0][1]);
            fma4(acc[m][0], a[m].y, w[1][0]); fma4(acc[m][1], a[m].y, w[1][1]);
            fma4(acc[m][0], a[m].z, w[2][0]); fma4(acc[m][1], a[m].z, w[2][1]);
            fma4(acc[m][0], a[m].w, w[3][0]); fma4(acc[m][1], a[m].w, w[3][1]);
        }
    }

    float4 bb0 = ((const float4*)bias)[cgp * 2 + 0];
    float4 bb1 = ((const float4*)bias)[cgp * 2 + 1];
    int os = cgp >> 1, oh = cgp & 1;
#pragma unroll
    for (int m = 0; m < 4; ++m) {
        int gr = row0 + rbase + m;
        if (gr < N) {
            float ndr = nd[gr];
            float4 o0, o1;
            o0.x = fmaxf(fmaf(acc[m][0].x, ndr, bb0.x), 0.f);
            o0.y = fmaxf(fmaf(acc[m][0].y, ndr, bb0.y), 0.f);
            o0.z = fmaxf(fmaf(acc[m][0].z, ndr, bb0.z), 0.f);
            o0.w = fmaxf(fmaf(acc[m][0].w, ndr, bb0.w), 0.f);
            o1.x = fmaxf(fmaf(acc[m][1].x, ndr, bb1.x), 0.f);
            o1.y = fmaxf(fmaf(acc[m][1].y, ndr, bb1.y), 0.f);
            o1.z = fmaxf(fmaf(acc[m][1].z, ndr, bb1.z), 0.f);
            o1.w = fmaxf(fmaf(acc[m][1].w, ndr, bb1.w), 0.f);
            if (SCALE_NS) {
                float s = ns[gr];
                o0.x *= s; o0.y *= s; o0.z *= s; o0.w *= s;
                o1.x *= s; o1.y *= s; o1.z *= s; o1.w *= s;
            }
            ((int4*)out)[(size_t)os * N * 2 + (size_t)gr * 2 + oh] = pack_h8(o0, o1);
        }
    }
}

// ---------------- GEMM 128(slab fp16) -> 40, *ns, output 5 slabs of int4 (8 halves) ----------

__global__ __launch_bounds__(256) void gemm40_kernel(const __half* __restrict__ A, const float* __restrict__ W,
                                                     const float* __restrict__ ns, __half* __restrict__ y, int N) {
    __shared__ float Ws[128 * NCLS];   // 20 KB
    __shared__ float As[32 * 132];     // 16.5 KB
    __shared__ __half ys[32][40];      // 2.5 KB
    int t = threadIdx.x;
    int row0 = blockIdx.x * 32;

#pragma unroll
    for (int i = 0; i < 5; ++i) {
        int idx = t + 256 * i;
        ((float4*)Ws)[idx] = ((const float4*)W)[idx];
    }
#pragma unroll
    for (int i = 0; i < 2; ++i) {
        int idx = t + 256 * i;        // 0..511
        int s = idx >> 6;
        int rem = idx & 63;
        int r = rem >> 1;
        int h = rem & 1;
        int gr = row0 + r;
        int4 v = make_int4(0, 0, 0, 0);
        if (gr < N) v = ((const int4*)A)[(size_t)s * N * 2 + (size_t)gr * 2 + h];
        const __half2* hh = (const __half2*)&v;
        float2 f0 = __half22float2(hh[0]);
        float2 f1 = __half22float2(hh[1]);
        float2 f2 = __half22float2(hh[2]);
        float2 f3 = __half22float2(hh[3]);
        float* dp = &As[r * 132 + (s * 2 + h) * 8];
        dp[0] = f0.x; dp[1] = f0.y; dp[2] = f1.x; dp[3] = f1.y;
        dp[4] = f2.x; dp[5] = f2.y; dp[6] = f3.x; dp[7] = f3.y;
    }
    __syncthreads();

    int row = t >> 3;
    int cg = t & 7;
    float acc[5] = {0.f, 0.f, 0.f, 0.f, 0.f};
#pragma unroll 2
    for (int k4 = 0; k4 < 32; ++k4) {
        float4 a = *(const float4*)&As[row * 132 + k4 * 4];
#pragma unroll
        for (int j = 0; j < 4; ++j) {
            float av = (j == 0) ? a.x : (j == 1) ? a.y : (j == 2) ? a.z : a.w;
            const float* wp = &Ws[(k4 * 4 + j) * NCLS + cg * 5];
            acc[0] = fmaf(av, wp[0], acc[0]);
            acc[1] = fmaf(av, wp[1], acc[1]);
            acc[2] = fmaf(av, wp[2], acc[2]);
            acc[3] = fmaf(av, wp[3], acc[3]);
            acc[4] = fmaf(av, wp[4], acc[4]);
        }
    }
    {
        int gr = row0 + row;
        float s = (gr < N) ? ns[gr] : 0.f;
        __half* yp = &ys[row][cg * 5];
        yp[0] = __float2half_rn(acc[0] * s);
        yp[1] = __float2half_rn(acc[1] * s);
        yp[2] = __float2half_rn(acc[2] * s);
        yp[3] = __float2half_rn(acc[3] * s);
        yp[4] = __float2half_rn(acc[4] * s);
    }
    __syncthreads();
    if (t < 160) {
        int s = t >> 5;      // 0..4
        int r = t & 31;
        int gr = row0 + r;
        if (gr < N) ((int4*)y)[(size_t)s * N + gr] = *(const int4*)&ys[r][s * 8];
    }
}

// ---------------- slab gather 40-d + *nd + b2 -> out (fp32) ----------------

__global__ __launch_bounds__(256) void gather40f(const __half* __restrict__ y, const int* __restrict__ csr,
                                                 const int* __restrict__ cursor, const float* __restrict__ nd,
                                                 const float* __restrict__ b2, float* __restrict__ out, int N) {
    int bid = blockIdx.x;
    int slice = bid % 5;
    int rb = bid / 5;
    int r = rb * 256 + threadIdx.x;
    if (r >= N) return;
    const int4* ys = (const int4*)y + (size_t)slice * N;
    int start = r ? cursor[r - 1] : 0;
    int end = cursor[r];
    float4 a0 = zero4(), a1 = zero4();
    int e = start;
    for (; e + 4 <= end; e += 4) {
        int i0 = csr[e + 0], i1 = csr[e + 1], i2 = csr[e + 2], i3 = csr[e + 3];
        int4 v0 = ys[i0];
        int4 v1 = ys[i1];
        int4 v2 = ys[i2];
        int4 v3 = ys[i3];
        add_h8(a0, a1, v0); add_h8(a0, a1, v1);
        add_h8(a0, a1, v2); add_h8(a0, a1, v3);
    }
    for (; e < end; ++e) {
        int4 v0 = ys[csr[e]];
        add_h8(a0, a1, v0);
    }
    float s = nd[r];
    const float* bp = b2 + slice * 8;
    float4 o0, o1;
    o0.x = fmaf(a0.x, s, bp[0]); o0.y = fmaf(a0.y, s, bp[1]);
    o0.z = fmaf(a0.z, s, bp[2]); o0.w = fmaf(a0.w, s, bp[3]);
    o1.x = fmaf(a1.x, s, bp[4]); o1.y = fmaf(a1.y, s, bp[5]);
    o1.z = fmaf(a1.z, s, bp[6]); o1.w = fmaf(a1.w, s, bp[7]);
    float* op = out + (size_t)r * NCLS + slice * 8;
    *(float4*)(op + 0) = o0;
    *(float4*)(op + 4) = o1;
}

extern "C" void kernel_launch(void* const* d_in, const int* in_sizes, int n_in,
                              void* d_out, int out_size, void* d_ws, size_t ws_size,
                              hipStream_t stream) {
    const float* x  = (const float*)d_in[0];
    const int* src  = (const int*)d_in[1];
    const int* dst  = (const int*)d_in[2];
    const float* W0 = (const float*)d_in[3];
    const float* b0 = (const float*)d_in[4];
    const float* W1 = (const float*)d_in[5];
    const float* b1 = (const float*)d_in[6];
    const float* W2 = (const float*)d_in[7];
    const float* b2 = (const float*)d_in[8];
    float* out = (float*)d_out;

    int N = in_sizes[0] / IN_DIM;
    int E = in_sizes[1];

    float* base = (float*)d_ws;
    float* ns   = base;                       // N
    float* ndn  = base + (size_t)N;           // N
    int* dsg    = (int*)(base + 2 * (size_t)N);
    int* ddg    = (int*)(base + 3 * (size_t)N);
    int* cursor = (int*)(base + 4 * (size_t)N);
    int* bsums  = (int*)(base + 5 * (size_t)N);          // 1024
    int* csr    = (int*)(base + 5 * (size_t)N + 1024);   // E
    __half* B0  = (__half*)(csr + (size_t)E);            // N x 128 halves (slabs)
    __half* B1  = B0 + (size_t)N * 128;                  // N x 128 halves (slabs)
    __half* B2  = B1 + (size_t)N * 128;                  // N x 128 halves (slabs)
    __half* yh  = B2 + (size_t)N * 128;                  // 5 slabs x N int4

    int nb = (N + 1023) / 1024;

    (void)hipMemsetAsync(dsg, 0, 2 * (size_t)N * sizeof(int), stream);
    deg_sliced<<<DEG_BLKS * 8, 256, 0, stream>>>(src, dst, dsg, ddg, E, N);
    norm_kernel<<<(N + 255) / 256, 256, 0, stream>>>(dsg, ddg, ns, ndn, N);

    scan_partial<<<nb, 256, 0, stream>>>(ddg, bsums, N);
    scan_bsums<<<1, 128, 0, stream>>>(bsums, nb);
    scan_final<<<nb, 256, 0, stream>>>(ddg, bsums, cursor, N);
    fill_csr_sliced<<<DEG_BLKS * 8, 256, 0, stream>>>(src, dst, cursor, csr, E, N);

    // B0 = slabbed fp16(x * ns)
    prescale_kernel<<<(N * 16 + 255) / 256, 256, 0, stream>>>(x, ns, B0, N);

    int nrb = (N + 127) / 128;
    int g64 = (N + 63) / 64;
    int nrb256 = (N + 255) / 256;

    // layer 0: B1 = spmm(B0) ; B2 = relu(B1*nd @ W0 + b0)*ns   (all slabbed)
    spmm16s<<<nrb * 8, 256, 0, stream>>>(B0, csr, cursor, B1, N);
    gemm128h<1><<<g64, 256, 0, stream>>>(B1, ndn, ns, W0, b0, B2, N);

    // layer 1: B1 = spmm(B2) ; B0 = relu(B1*nd @ W1 + b1)
    spmm16s<<<nrb * 8, 256, 0, stream>>>(B2, csr, cursor, B1, N);
    gemm128h<0><<<g64, 256, 0, stream>>>(B1, ndn, ns, W1, b1, B0, N);

    // layer 2: yh = (B0 @ W2)*ns (5 slabs) ; out = gather40(yh)*nd + b2
    gemm40_kernel<<<(N + 31) / 32, 256, 0, stream>>>(B0, W2, ns, yh, N);
    gather40f<<<nrb256 * 5, 256, 0, stream>>>(yh, csr, cursor, ndn, b2, out, N);
}

// Round 13
// 630.351 us; speedup vs baseline: 1.4483x; 1.1010x over previous
//
#include <hip/hip_runtime.h>
#include <hip/hip_fp16.h>

#define IN_DIM 128
#define NCLS 40
#define AS_STRIDE 136   // halves; 272 B row stride
#define SLICE_MAX 12544 // max nodes per 1/8 slice (N<=100352)
#define HB 32           // edge chunks (blocks per slice)

// ---------------- sliced LDS histogram (no global atomics) ----------------
// grid = 8*HB; slice = bid&7, chunk = bid>>3. Counts idx[] hits in node range
// [slice*chunkN, ...) over edge chunk; flushes LDS hist to staging with plain stores.

__global__ __launch_bounds__(256) void hist_sliced(const int* __restrict__ idx, int* __restrict__ staging,
                                                   int E, int N) {
    __shared__ int hist[SLICE_MAX];
    int bid = blockIdx.x;
    int slice = bid & 7;
    int b = bid >> 3;
    int chunkN = (N + 7) >> 3;
    int lo = slice * chunkN;
    int hi = min(lo + chunkN, N);
    int t = threadIdx.x;
    for (int i = t; i < SLICE_MAX; i += 256) hist[i] = 0;
    __syncthreads();
    int ce = (E + HB - 1) / HB;
    int e0 = b * ce, e1 = min(e0 + ce, E);
    int nv = (e1 - e0) >> 2;
    const int4* iv = (const int4*)(idx + e0);
    for (int k = t; k < nv; k += 256) {
        int4 d = iv[k];
        if (d.x >= lo && d.x < hi) atomicAdd(&hist[d.x - lo], 1);
        if (d.y >= lo && d.y < hi) atomicAdd(&hist[d.y - lo], 1);
        if (d.z >= lo && d.z < hi) atomicAdd(&hist[d.z - lo], 1);
        if (d.w >= lo && d.w < hi) atomicAdd(&hist[d.w - lo], 1);
    }
    for (int e = e0 + nv * 4 + t; e < e1; e += 256) {
        int d = idx[e];
        if (d >= lo && d < hi) atomicAdd(&hist[d - lo], 1);
    }
    __syncthreads();
    int* sp = staging + (size_t)(slice * HB + b) * SLICE_MAX;
    for (int i = t; i < chunkN; i += 256) sp[i] = hist[i];
}

// ---------------- reduce staging -> degree; optionally write back exclusive prefix ----------

template<int SCANBACK>
__global__ __launch_bounds__(256) void reduce_staging(int* __restrict__ staging, int* __restrict__ deg, int N) {
    int i = blockIdx.x * 256 + threadIdx.x;
    if (i >= N) return;
    int chunkN = (N + 7) >> 3;
    int slice = i / chunkN;
    int li = i - slice * chunkN;
    int* basep = staging + (size_t)slice * HB * SLICE_MAX + li;
    int acc = 0;
#pragma unroll
    for (int b = 0; b < HB; ++b) {
        int* p = basep + (size_t)b * SLICE_MAX;
        int v = *p;
        if (SCANBACK) *p = acc;
        acc += v;
    }
    deg[i] = acc;
}

__global__ __launch_bounds__(256) void norm_kernel(const int* __restrict__ ds, const int* __restrict__ dd,
                                                   float* __restrict__ ns, float* __restrict__ nd, int N) {
    int i = blockIdx.x * 256 + threadIdx.x;
    if (i < N) {
        ns[i] = ds[i] > 0 ? rsqrtf((float)ds[i]) : 0.f;
        nd[i] = dd[i] > 0 ? rsqrtf((float)dd[i]) : 0.f;
    }
}

// ---------------- exclusive scan of in-degrees -> row starts cursor[0..N] ----------------

__global__ __launch_bounds__(256) void scan_partial(const int* __restrict__ dd, int* __restrict__ bsums, int N) {
    __shared__ int sd[256];
    int t = threadIdx.x;
    int base = blockIdx.x * 1024 + t * 4;
    int s = 0;
#pragma unroll
    for (int k = 0; k < 4; ++k) { int i = base + k; if (i < N) s += dd[i]; }
    sd[t] = s;
    __syncthreads();
    for (int off = 128; off > 0; off >>= 1) {
        if (t < off) sd[t] += sd[t + off];
        __syncthreads();
    }
    if (t == 0) bsums[blockIdx.x] = sd[0];
}

__global__ __launch_bounds__(128) void scan_bsums(int* __restrict__ bsums, int nb) {
    __shared__ int sd[128];
    __shared__ int carry_s;
    int t = threadIdx.x;
    if (t == 0) carry_s = 0;
    __syncthreads();
    for (int base = 0; base < nb; base += 128) {
        int i = base + t;
        int orig = (i < nb) ? bsums[i] : 0;
        sd[t] = orig;
        __syncthreads();
        for (int off = 1; off < 128; off <<= 1) {
            int u = (t >= off) ? sd[t - off] : 0;
            __syncthreads();
            sd[t] += u;
            __syncthreads();
        }
        int carry = carry_s;
        if (i < nb) bsums[i] = carry + sd[t] - orig;   // exclusive
        __syncthreads();
        if (t == 127) carry_s = carry + sd[127];
        __syncthreads();
    }
}

__global__ __launch_bounds__(256) void scan_final(const int* __restrict__ dd, const int* __restrict__ bsums,
                                                  int* __restrict__ cursor, int N) {
    __shared__ int sd[256];
    int t = threadIdx.x;
    int base = blockIdx.x * 1024 + t * 4;
    int v[4]; int s = 0;
#pragma unroll
    for (int k = 0; k < 4; ++k) { int i = base + k; v[k] = (i < N) ? dd[i] : 0; s += v[k]; }
    sd[t] = s;
    __syncthreads();
    for (int off = 1; off < 256; off <<= 1) {
        int u = (t >= off) ? sd[t - off] : 0;
        __syncthreads();
        sd[t] += u;
        __syncthreads();
    }
    int excl = sd[t] - s + bsums[blockIdx.x];
#pragma unroll
    for (int k = 0; k < 4; ++k) {
        int i = base + k;
        if (i < N) {
            cursor[i] = excl;       // exclusive row start
            excl += v[k];
            if (i == N - 1) cursor[N] = excl;
        }
    }
}

// ---------------- CSR fill: LDS cursors (rowstart + staged prefix), no global atomics -------

__global__ __launch_bounds__(256) void fill_noatomic(const int* __restrict__ src, const int* __restrict__ dst,
                                                     const int* __restrict__ rowstart, const int* __restrict__ staging,
                                                     int* __restrict__ csr, int E, int N) {
    __shared__ int cur[SLICE_MAX];
    int bid = blockIdx.x;
    int slice = bid & 7;
    int b = bid >> 3;
    int chunkN = (N + 7) >> 3;
    int lo = slice * chunkN;
    int hi = min(lo + chunkN, N);
    int t = threadIdx.x;
    const int* sp = staging + (size_t)(slice * HB + b) * SLICE_MAX;
    for (int i = t; i < chunkN; i += 256) cur[i] = rowstart[lo + i] + sp[i];
    __syncthreads();
    int ce = (E + HB - 1) / HB;
    int e0 = b * ce, e1 = min(e0 + ce, E);
    int nv = (e1 - e0) >> 2;
    const int4* dv4 = (const int4*)(dst + e0);
    const int4* sv4 = (const int4*)(src + e0);
    for (int k = t; k < nv; k += 256) {
        int4 d = dv4[k];
        int4 sv = sv4[k];
        if (d.x >= lo && d.x < hi) csr[atomicAdd(&cur[d.x - lo], 1)] = sv.x;
        if (d.y >= lo && d.y < hi) csr[atomicAdd(&cur[d.y - lo], 1)] = sv.y;
        if (d.z >= lo && d.z < hi) csr[atomicAdd(&cur[d.z - lo], 1)] = sv.z;
        if (d.w >= lo && d.w < hi) csr[atomicAdd(&cur[d.w - lo], 1)] = sv.w;
    }
    for (int e = e0 + nv * 4 + t; e < e1; e += 256) {
        int d = dst[e];
        if (d >= lo && d < hi) csr[atomicAdd(&cur[d - lo], 1)] = src[e];
    }
}

// ---------------- helpers ----------------

__device__ __forceinline__ float4 zero4() { return make_float4(0.f, 0.f, 0.f, 0.f); }

__device__ __forceinline__ void fma4(float4& acc, float s, const float4& wv) {
    acc.x = fmaf(s, wv.x, acc.x);
    acc.y = fmaf(s, wv.y, acc.y);
    acc.z = fmaf(s, wv.z, acc.z);
    acc.w = fmaf(s, wv.w, acc.w);
}

__device__ __forceinline__ void add_h8(float4& a0, float4& a1, const int4& v) {
    const __half2* h = (const __half2*)&v;
    float2 f0 = __half22float2(h[0]);
    float2 f1 = __half22float2(h[1]);
    float2 f2 = __half22float2(h[2]);
    float2 f3 = __half22float2(h[3]);
    a0.x += f0.x; a0.y += f0.y; a0.z += f1.x; a0.w += f1.y;
    a1.x += f2.x; a1.y += f2.y; a1.z += f3.x; a1.w += f3.y;
}

__device__ __forceinline__ int4 pack_h8(const float4& o0, const float4& o1) {
    int4 p;
    __half2* ph = (__half2*)&p;
    ph[0] = __float22half2_rn(make_float2(o0.x, o0.y));
    ph[1] = __float22half2_rn(make_float2(o0.z, o0.w));
    ph[2] = __float22half2_rn(make_float2(o1.x, o1.y));
    ph[3] = __float22half2_rn(make_float2(o1.z, o1.w));
    return p;
}

// ---------------- prescale into slabs: slab s holds halves [16s,16s+16) of every row ----------

__global__ __launch_bounds__(256) void prescale_kernel(const float* __restrict__ x, const float* __restrict__ ns,
                                                       __half* __restrict__ xs, int N) {
    int tid = blockIdx.x * 256 + threadIdx.x;     // over 16N int4s, slab-major
    if (tid >= N * 16) return;
    int s = tid / (2 * N);
    int rem = tid - s * 2 * N;
    int n = rem >> 1;
    int h = rem & 1;
    float sc = ns[n];
    const float4* xp = (const float4*)x + (size_t)n * 32 + (s * 2 + h) * 2;
    float4 v0 = xp[0], v1 = xp[1];
    v0.x *= sc; v0.y *= sc; v0.z *= sc; v0.w *= sc;
    v1.x *= sc; v1.y *= sc; v1.z *= sc; v1.w *= sc;
    ((int4*)xs)[tid] = pack_h8(v0, v1);
}

// ---------------- slab SpMM: agg_slab[s][r] = sum_{src in N(r)} x_slab[s][src] ----------------

__global__ __launch_bounds__(256) void spmm16s(const __half* __restrict__ xs, const int* __restrict__ csr,
                                               const int* __restrict__ cursor, __half* __restrict__ as_, int N) {
    int bid = blockIdx.x;
    int slice = bid & 7;
    int rb = bid >> 3;
    int r = rb * 128 + (threadIdx.x >> 1);
    if (r >= N) return;
    int h = threadIdx.x & 1;
    const int4* xi = (const int4*)xs + (size_t)slice * N * 2;
    int start = cursor[r];
    int end = cursor[r + 1];
    float4 a0 = zero4(), a1 = zero4();
    int e = start;
    for (; e + 4 <= end; e += 4) {
        int i0 = csr[e + 0], i1 = csr[e + 1], i2 = csr[e + 2], i3 = csr[e + 3];
        int4 v0 = xi[(size_t)i0 * 2 + h];
        int4 v1 = xi[(size_t)i1 * 2 + h];
        int4 v2 = xi[(size_t)i2 * 2 + h];
        int4 v3 = xi[(size_t)i3 * 2 + h];
        add_h8(a0, a1, v0); add_h8(a0, a1, v1);
        add_h8(a0, a1, v2); add_h8(a0, a1, v3);
    }
    for (; e < end; ++e) {
        int4 v0 = xi[(size_t)csr[e] * 2 + h];
        add_h8(a0, a1, v0);
    }
    ((int4*)as_)[(size_t)slice * N * 2 + (size_t)r * 2 + h] = pack_h8(a0, a1);
}

// ---------------- GEMM 128(fp16 slab agg) -> 128, epilogue acc*nd+bias, relu, (*ns) -> slabs --

template<int SCALE_NS>
__global__ __launch_bounds__(256, 6) void gemm128h(const __half* __restrict__ agg, const float* __restrict__ nd,
                                                   const float* __restrict__ ns, const float* __restrict__ W,
                                                   const float* __restrict__ bias, __half* __restrict__ out, int N) {
    __shared__ __half As[64 * AS_STRIDE];
    int t = threadIdx.x;
    int row0 = blockIdx.x * 64;

#pragma unroll
    for (int i = 0; i < 4; ++i) {
        int idx = t + 256 * i;          // 0..1023
        int s = idx >> 7;
        int rem = idx & 127;
        int r = rem >> 1;
        int h = rem & 1;
        int gr = row0 + r;
        int4 v = make_int4(0, 0, 0, 0);
        if (gr < N) v = ((const int4*)agg)[(size_t)s * N * 2 + (size_t)gr * 2 + h];
        *(int4*)&As[r * AS_STRIDE + (s * 2 + h) * 8] = v;
    }
    __syncthreads();

    int rg = t >> 4;
    int cgp = t & 15;
    int rbase = rg * 4;
    const float4* Wg = (const float4*)W;
    float4 acc[4][2];
#pragma unroll
    for (int m = 0; m < 4; ++m) { acc[m][0] = zero4(); acc[m][1] = zero4(); }
#pragma unroll 2
    for (int k4 = 0; k4 < 32; ++k4) {
        int k0 = k4 * 4;
        float4 a[4];
#pragma unroll
        for (int m = 0; m < 4; ++m) {
            uint2 raw = *(const uint2*)&As[(rbase + m) * AS_STRIDE + k0];
            const __half2* hp = (const __half2*)&raw;
            float2 f0 = __half22float2(hp[0]);
            float2 f1 = __half22float2(hp[1]);
            a[m] = make_float4(f0.x, f0.y, f1.x, f1.y);
        }
        float4 w[4][2];
#pragma unroll
        for (int j = 0; j < 4; ++j) {
            w[j][0] = Wg[(k0 + j) * 32 + cgp * 2 + 0];
            w[j][1] = Wg[(k0 + j) * 32 + cgp * 2 + 1];
        }
#pragma unroll
        for (int m = 0; m < 4; ++m) {
            fma4(acc[m][0], a[m].x, w[0][0]); fma4(acc[m][1], a[m].x, w[0][1]);
            fma4(acc[m][0], a[m].y, w[1][0]); fma4(acc[m][1], a[m].y, w[1][1]);
            fma4(acc[m][0], a[m].z, w[2][0]); fma4(acc[m][1], a[m].z, w[2][1]);
            fma4(acc[m][0], a[m].w, w[3][0]); fma4(acc[m][1], a[m].w, w[3][1]);
        }
    }

    float4 bb0 = ((const float4*)bias)[cgp * 2 + 0];
    float4 bb1 = ((const float4*)bias)[cgp * 2 + 1];
    int os = cgp >> 1, oh = cgp & 1;
#pragma unroll
    for (int m = 0; m < 4; ++m) {
        int gr = row0 + rbase + m;
        if (gr < N) {
            float ndr = nd[gr];
            float4 o0, o1;
            o0.x = fmaxf(fmaf(acc[m][0].x, ndr, bb0.x), 0.f);
            o0.y = fmaxf(fmaf(acc[m][0].y, ndr, bb0.y), 0.f);
            o0.z = fmaxf(fmaf(acc[m][0].z, ndr, bb0.z), 0.f);
            o0.w = fmaxf(fmaf(acc[m][0].w, ndr, bb0.w), 0.f);
            o1.x = fmaxf(fmaf(acc[m][1].x, ndr, bb1.x), 0.f);
            o1.y = fmaxf(fmaf(acc[m][1].y, ndr, bb1.y), 0.f);
            o1.z = fmaxf(fmaf(acc[m][1].z, ndr, bb1.z), 0.f);
            o1.w = fmaxf(fmaf(acc[m][1].w, ndr, bb1.w), 0.f);
            if (SCALE_NS) {
                float s = ns[gr];
                o0.x *= s; o0.y *= s; o0.z *= s; o0.w *= s;
                o1.x *= s; o1.y *= s; o1.z *= s; o1.w *= s;
            }
            ((int4*)out)[(size_t)os * N * 2 + (size_t)gr * 2 + oh] = pack_h8(o0, o1);
        }
    }
}

// ---------------- GEMM 128(slab fp16) -> 40, *ns, output 5 slabs of int4 (8 halves) ----------

__global__ __launch_bounds__(256) void gemm40_kernel(const __half* __restrict__ A, const float* __restrict__ W,
                                                     const float* __restrict__ ns, __half* __restrict__ y, int N) {
    __shared__ float Ws[128 * NCLS];   // 20 KB
    __shared__ float As[32 * 132];     // 16.5 KB
    __shared__ __half ys[32][40];      // 2.5 KB
    int t = threadIdx.x;
    int row0 = blockIdx.x * 32;

#pragma unroll
    for (int i = 0; i < 5; ++i) {
        int idx = t + 256 * i;
        ((float4*)Ws)[idx] = ((const float4*)W)[idx];
    }
#pragma unroll
    for (int i = 0; i < 2; ++i) {
        int idx = t + 256 * i;        // 0..511
        int s = idx >> 6;
        int rem = idx & 63;
        int r = rem >> 1;
        int h = rem & 1;
        int gr = row0 + r;
        int4 v = make_int4(0, 0, 0, 0);
        if (gr < N) v = ((const int4*)A)[(size_t)s * N * 2 + (size_t)gr * 2 + h];
        const __half2* hh = (const __half2*)&v;
        float2 f0 = __half22float2(hh[0]);
        float2 f1 = __half22float2(hh[1]);
        float2 f2 = __half22float2(hh[2]);
        float2 f3 = __half22float2(hh[3]);
        float* dp = &As[r * 132 + (s * 2 + h) * 8];
        dp[0] = f0.x; dp[1] = f0.y; dp[2] = f1.x; dp[3] = f1.y;
        dp[4] = f2.x; dp[5] = f2.y; dp[6] = f3.x; dp[7] = f3.y;
    }
    __syncthreads();

    int row = t >> 3;
    int cg = t & 7;
    float acc[5] = {0.f, 0.f, 0.f, 0.f, 0.f};
#pragma unroll 2
    for (int k4 = 0; k4 < 32; ++k4) {
        float4 a = *(const float4*)&As[row * 132 + k4 * 4];
#pragma unroll
        for (int j = 0; j < 4; ++j) {
            float av = (j == 0) ? a.x : (j == 1) ? a.y : (j == 2) ? a.z : a.w;
            const float* wp = &Ws[(k4 * 4 + j) * NCLS + cg * 5];
            acc[0] = fmaf(av, wp[0], acc[0]);
            acc[1] = fmaf(av, wp[1], acc[1]);
            acc[2] = fmaf(av, wp[2], acc[2]);
            acc[3] = fmaf(av, wp[3], acc[3]);
            acc[4] = fmaf(av, wp[4], acc[4]);
        }
    }
    {
        int gr = row0 + row;
        float s = (gr < N) ? ns[gr] : 0.f;
        __half* yp = &ys[row][cg * 5];
        yp[0] = __float2half_rn(acc[0] * s);
        yp[1] = __float2half_rn(acc[1] * s);
        yp[2] = __float2half_rn(acc[2] * s);
        yp[3] = __float2half_rn(acc[3] * s);
        yp[4] = __float2half_rn(acc[4] * s);
    }
    __syncthreads();
    if (t < 160) {
        int s = t >> 5;      // 0..4
        int r = t & 31;
        int gr = row0 + r;
        if (gr < N) ((int4*)y)[(size_t)s * N + gr] = *(const int4*)&ys[r][s * 8];
    }
}

// ---------------- slab gather 40-d + *nd + b2 -> out (fp32) ----------------

__global__ __launch_bounds__(256) void gather40f(const __half* __restrict__ y, const int* __restrict__ csr,
                                                 const int* __restrict__ cursor, const float* __restrict__ nd,
                                                 const float* __restrict__ b2, float* __restrict__ out, int N) {
    int bid = blockIdx.x;
    int slice = bid % 5;
    int rb = bid / 5;
    int r = rb * 256 + threadIdx.x;
    if (r >= N) return;
    const int4* ys = (const int4*)y + (size_t)slice * N;
    int start = cursor[r];
    int end = cursor[r + 1];
    float4 a0 = zero4(), a1 = zero4();
    int e = start;
    for (; e + 4 <= end; e += 4) {
        int i0 = csr[e + 0], i1 = csr[e + 1], i2 = csr[e + 2], i3 = csr[e + 3];
        int4 v0 = ys[i0];
        int4 v1 = ys[i1];
        int4 v2 = ys[i2];
        int4 v3 = ys[i3];
        add_h8(a0, a1, v0); add_h8(a0, a1, v1);
        add_h8(a0, a1, v2); add_h8(a0, a1, v3);
    }
    for (; e < end; ++e) {
        int4 v0 = ys[csr[e]];
        add_h8(a0, a1, v0);
    }
    float s = nd[r];
    const float* bp = b2 + slice * 8;
    float4 o0, o1;
    o0.x = fmaf(a0.x, s, bp[0]); o0.y = fmaf(a0.y, s, bp[1]);
    o0.z = fmaf(a0.z, s, bp[2]); o0.w = fmaf(a0.w, s, bp[3]);
    o1.x = fmaf(a1.x, s, bp[4]); o1.y = fmaf(a1.y, s, bp[5]);
    o1.z = fmaf(a1.z, s, bp[6]); o1.w = fmaf(a1.w, s, bp[7]);
    float* op = out + (size_t)r * NCLS + slice * 8;
    *(float4*)(op + 0) = o0;
    *(float4*)(op + 4) = o1;
}

extern "C" void kernel_launch(void* const* d_in, const int* in_sizes, int n_in,
                              void* d_out, int out_size, void* d_ws, size_t ws_size,
                              hipStream_t stream) {
    const float* x  = (const float*)d_in[0];
    const int* src  = (const int*)d_in[1];
    const int* dst  = (const int*)d_in[2];
    const float* W0 = (const float*)d_in[3];
    const float* b0 = (const float*)d_in[4];
    const float* W1 = (const float*)d_in[5];
    const float* b1 = (const float*)d_in[6];
    const float* W2 = (const float*)d_in[7];
    const float* b2 = (const float*)d_in[8];
    float* out = (float*)d_out;

    int N = in_sizes[0] / IN_DIM;
    int E = in_sizes[1];

    float* base = (float*)d_ws;
    float* ns   = base;                       // N
    float* ndn  = base + (size_t)N;           // N
    int* dsg    = (int*)(base + 2 * (size_t)N);
    int* ddg    = dsg + (size_t)N;
    int* cursor = ddg + (size_t)N;            // N+1
    int* bsums  = cursor + (size_t)N + 1;     // 1024
    int* csr    = bsums + 1024;               // E
    __half* B0  = (__half*)(csr + (size_t)E); // N x 128 halves (slabs)
    __half* B1  = B0 + (size_t)N * 128;       // N x 128 halves (slabs)
    __half* B2  = B1 + (size_t)N * 128;       // N x 128 halves (slabs)
    __half* yh  = B2 + (size_t)N * 128;       // 5 slabs x N int4
    int* staging = (int*)B1;                  // 8*HB*SLICE_MAX ints (12.9 MB), dead before B1 is written

    int nb = (N + 1023) / 1024;
    int gN = (N + 255) / 256;

    // degrees via sliced LDS histograms (no global atomics)
    hist_sliced<<<8 * HB, 256, 0, stream>>>(src, staging, E, N);
    reduce_staging<0><<<gN, 256, 0, stream>>>(staging, dsg, N);
    hist_sliced<<<8 * HB, 256, 0, stream>>>(dst, staging, E, N);
    reduce_staging<1><<<gN, 256, 0, stream>>>(staging, ddg, N);   // + exclusive prefix scanback
    norm_kernel<<<gN, 256, 0, stream>>>(dsg, ddg, ns, ndn, N);

    // row starts
    scan_partial<<<nb, 256, 0, stream>>>(ddg, bsums, N);
    scan_bsums<<<1, 128, 0, stream>>>(bsums, nb);
    scan_final<<<nb, 256, 0, stream>>>(ddg, bsums, cursor, N);

    // CSR fill: LDS cursors, plain csr stores
    fill_noatomic<<<8 * HB, 256, 0, stream>>>(src, dst, cursor, staging, csr, E, N);

    // B0 = slabbed fp16(x * ns)
    prescale_kernel<<<(N * 16 + 255) / 256, 256, 0, stream>>>(x, ns, B0, N);

    int nrb = (N + 127) / 128;
    int g64 = (N + 63) / 64;
    int nrb256 = (N + 255) / 256;

    // layer 0: B1 = spmm(B0) ; B2 = relu(B1*nd @ W0 + b0)*ns   (all slabbed)
    spmm16s<<<nrb * 8, 256, 0, stream>>>(B0, csr, cursor, B1, N);
    gemm128h<1><<<g64, 256, 0, stream>>>(B1, ndn, ns, W0, b0, B2, N);

    // layer 1: B1 = spmm(B2) ; B0 = relu(B1*nd @ W1 + b1)
    spmm16s<<<nrb * 8, 256, 0, stream>>>(B2, csr, cursor, B1, N);
    gemm128h<0><<<g64, 256, 0, stream>>>(B1, ndn, ns, W1, b1, B0, N);

    // layer 2: yh = (B0 @ W2)*ns (5 slabs) ; out = gather40(yh)*nd + b2
    gemm40_kernel<<<(N + 31) / 32, 256, 0, stream>>>(B0, W2, ns, yh, N);
    gather40f<<<nrb256 * 5, 256, 0, stream>>>(yh, csr, cursor, ndn, b2, out, N);
}

// Round 14
// 593.637 us; speedup vs baseline: 1.5379x; 1.0618x over previous
//
#include <hip/hip_runtime.h>
#include <hip/hip_fp16.h>

#define IN_DIM 128
#define NCLS 40
#define AS_STRIDE 136   // halves; 272 B row stride
#define SLICE_MAX 12544 // max nodes per 1/8 slice (N<=100352)
#define HB 32           // edge chunks (blocks per slice)

// ---------------- sliced LDS histogram (no global atomics) ----------------

__global__ __launch_bounds__(256) void hist_sliced(const int* __restrict__ idx, int* __restrict__ staging,
                                                   int E, int N) {
    __shared__ int hist[SLICE_MAX];
    int bid = blockIdx.x;
    int slice = bid & 7;
    int b = bid >> 3;
    int chunkN = (N + 7) >> 3;
    int lo = slice * chunkN;
    int hi = min(lo + chunkN, N);
    int t = threadIdx.x;
    for (int i = t; i < SLICE_MAX; i += 256) hist[i] = 0;
    __syncthreads();
    int ce = (E + HB - 1) / HB;
    int e0 = b * ce, e1 = min(e0 + ce, E);
    int nv = (e1 - e0) >> 2;
    const int4* iv = (const int4*)(idx + e0);
    for (int k = t; k < nv; k += 256) {
        int4 d = iv[k];
        if (d.x >= lo && d.x < hi) atomicAdd(&hist[d.x - lo], 1);
        if (d.y >= lo && d.y < hi) atomicAdd(&hist[d.y - lo], 1);
        if (d.z >= lo && d.z < hi) atomicAdd(&hist[d.z - lo], 1);
        if (d.w >= lo && d.w < hi) atomicAdd(&hist[d.w - lo], 1);
    }
    for (int e = e0 + nv * 4 + t; e < e1; e += 256) {
        int d = idx[e];
        if (d >= lo && d < hi) atomicAdd(&hist[d - lo], 1);
    }
    __syncthreads();
    int* sp = staging + (size_t)(slice * HB + b) * SLICE_MAX;
    for (int i = t; i < chunkN; i += 256) sp[i] = hist[i];
}

// ---------------- reduce staging -> degree; optionally write back exclusive prefix ----------

template<int SCANBACK>
__global__ __launch_bounds__(256) void reduce_staging(int* __restrict__ staging, int* __restrict__ deg, int N) {
    int i = blockIdx.x * 256 + threadIdx.x;
    if (i >= N) return;
    int chunkN = (N + 7) >> 3;
    int slice = i / chunkN;
    int li = i - slice * chunkN;
    int* basep = staging + (size_t)slice * HB * SLICE_MAX + li;
    int acc = 0;
#pragma unroll
    for (int b = 0; b < HB; ++b) {
        int* p = basep + (size_t)b * SLICE_MAX;
        int v = *p;
        if (SCANBACK) *p = acc;
        acc += v;
    }
    deg[i] = acc;
}

__global__ __launch_bounds__(256) void norm_kernel(const int* __restrict__ ds, const int* __restrict__ dd,
                                                   float* __restrict__ ns, float* __restrict__ nd, int N) {
    int i = blockIdx.x * 256 + threadIdx.x;
    if (i < N) {
        ns[i] = ds[i] > 0 ? rsqrtf((float)ds[i]) : 0.f;
        nd[i] = dd[i] > 0 ? rsqrtf((float)dd[i]) : 0.f;
    }
}

// ---------------- exclusive scan of in-degrees -> row starts cursor[0..N] ----------------

__global__ __launch_bounds__(256) void scan_partial(const int* __restrict__ dd, int* __restrict__ bsums, int N) {
    __shared__ int sd[256];
    int t = threadIdx.x;
    int base = blockIdx.x * 1024 + t * 4;
    int s = 0;
#pragma unroll
    for (int k = 0; k < 4; ++k) { int i = base + k; if (i < N) s += dd[i]; }
    sd[t] = s;
    __syncthreads();
    for (int off = 128; off > 0; off >>= 1) {
        if (t < off) sd[t] += sd[t + off];
        __syncthreads();
    }
    if (t == 0) bsums[blockIdx.x] = sd[0];
}

__global__ __launch_bounds__(128) void scan_bsums(int* __restrict__ bsums, int nb) {
    __shared__ int sd[128];
    __shared__ int carry_s;
    int t = threadIdx.x;
    if (t == 0) carry_s = 0;
    __syncthreads();
    for (int base = 0; base < nb; base += 128) {
        int i = base + t;
        int orig = (i < nb) ? bsums[i] : 0;
        sd[t] = orig;
        __syncthreads();
        for (int off = 1; off < 128; off <<= 1) {
            int u = (t >= off) ? sd[t - off] : 0;
            __syncthreads();
            sd[t] += u;
            __syncthreads();
        }
        int carry = carry_s;
        if (i < nb) bsums[i] = carry + sd[t] - orig;   // exclusive
        __syncthreads();
        if (t == 127) carry_s = carry + sd[127];
        __syncthreads();
    }
}

__global__ __launch_bounds__(256) void scan_final(const int* __restrict__ dd, const int* __restrict__ bsums,
                                                  int* __restrict__ cursor, int N) {
    __shared__ int sd[256];
    int t = threadIdx.x;
    int base = blockIdx.x * 1024 + t * 4;
    int v[4]; int s = 0;
#pragma unroll
    for (int k = 0; k < 4; ++k) { int i = base + k; v[k] = (i < N) ? dd[i] : 0; s += v[k]; }
    sd[t] = s;
    __syncthreads();
    for (int off = 1; off < 256; off <<= 1) {
        int u = (t >= off) ? sd[t - off] : 0;
        __syncthreads();
        sd[t] += u;
        __syncthreads();
    }
    int excl = sd[t] - s + bsums[blockIdx.x];
#pragma unroll
    for (int k = 0; k < 4; ++k) {
        int i = base + k;
        if (i < N) {
            cursor[i] = excl;       // exclusive row start
            excl += v[k];
            if (i == N - 1) cursor[N] = excl;
        }
    }
}

// ---------------- CSR fill: LDS cursors (rowstart + staged prefix), no global atomics -------

__global__ __launch_bounds__(256) void fill_noatomic(const int* __restrict__ src, const int* __restrict__ dst,
                                                     const int* __restrict__ rowstart, const int* __restrict__ staging,
                                                     int* __restrict__ csr, int E, int N) {
    __shared__ int cur[SLICE_MAX];
    int bid = blockIdx.x;
    int slice = bid & 7;
    int b = bid >> 3;
    int chunkN = (N + 7) >> 3;
    int lo = slice * chunkN;
    int hi = min(lo + chunkN, N);
    int t = threadIdx.x;
    const int* sp = staging + (size_t)(slice * HB + b) * SLICE_MAX;
    for (int i = t; i < chunkN; i += 256) cur[i] = rowstart[lo + i] + sp[i];
    __syncthreads();
    int ce = (E + HB - 1) / HB;
    int e0 = b * ce, e1 = min(e0 + ce, E);
    int nv = (e1 - e0) >> 2;
    const int4* dv4 = (const int4*)(dst + e0);
    const int4* sv4 = (const int4*)(src + e0);
    for (int k = t; k < nv; k += 256) {
        int4 d = dv4[k];
        int4 sv = sv4[k];
        if (d.x >= lo && d.x < hi) csr[atomicAdd(&cur[d.x - lo], 1)] = sv.x;
        if (d.y >= lo && d.y < hi) csr[atomicAdd(&cur[d.y - lo], 1)] = sv.y;
        if (d.z >= lo && d.z < hi) csr[atomicAdd(&cur[d.z - lo], 1)] = sv.z;
        if (d.w >= lo && d.w < hi) csr[atomicAdd(&cur[d.w - lo], 1)] = sv.w;
    }
    for (int e = e0 + nv * 4 + t; e < e1; e += 256) {
        int d = dst[e];
        if (d >= lo && d < hi) csr[atomicAdd(&cur[d - lo], 1)] = src[e];
    }
}

// ---------------- helpers ----------------

__device__ __forceinline__ float4 zero4() { return make_float4(0.f, 0.f, 0.f, 0.f); }

__device__ __forceinline__ void fma4(float4& acc, float s, const float4& wv) {
    acc.x = fmaf(s, wv.x, acc.x);
    acc.y = fmaf(s, wv.y, acc.y);
    acc.z = fmaf(s, wv.z, acc.z);
    acc.w = fmaf(s, wv.w, acc.w);
}

__device__ __forceinline__ void add_h8(float4& a0, float4& a1, const int4& v) {
    const __half2* h = (const __half2*)&v;
    float2 f0 = __half22float2(h[0]);
    float2 f1 = __half22float2(h[1]);
    float2 f2 = __half22float2(h[2]);
    float2 f3 = __half22float2(h[3]);
    a0.x += f0.x; a0.y += f0.y; a0.z += f1.x; a0.w += f1.y;
    a1.x += f2.x; a1.y += f2.y; a1.z += f3.x; a1.w += f3.y;
}

__device__ __forceinline__ int4 pack_h8(const float4& o0, const float4& o1) {
    int4 p;
    __half2* ph = (__half2*)&p;
    ph[0] = __float22half2_rn(make_float2(o0.x, o0.y));
    ph[1] = __float22half2_rn(make_float2(o0.z, o0.w));
    ph[2] = __float22half2_rn(make_float2(o1.x, o1.y));
    ph[3] = __float22half2_rn(make_float2(o1.z, o1.w));
    return p;
}

// ---------------- prescale into slabs: slab s holds halves [16s,16s+16) of every row ----------

__global__ __launch_bounds__(256) void prescale_kernel(const float* __restrict__ x, const float* __restrict__ ns,
                                                       __half* __restrict__ xs, int N) {
    int tid = blockIdx.x * 256 + threadIdx.x;     // over 16N int4s, slab-major
    if (tid >= N * 16) return;
    int s = tid / (2 * N);
    int rem = tid - s * 2 * N;
    int n = rem >> 1;
    int h = rem & 1;
    float sc = ns[n];
    const float4* xp = (const float4*)x + (size_t)n * 32 + (s * 2 + h) * 2;
    float4 v0 = xp[0], v1 = xp[1];
    v0.x *= sc; v0.y *= sc; v0.z *= sc; v0.w *= sc;
    v1.x *= sc; v1.y *= sc; v1.z *= sc; v1.w *= sc;
    ((int4*)xs)[tid] = pack_h8(v0, v1);
}

// ---------------- slab SpMM: agg_slab[s][r] = sum_{src in N(r)} x_slab[s][src] ----------------

__global__ __launch_bounds__(256) void spmm16s(const __half* __restrict__ xs, const int* __restrict__ csr,
                                               const int* __restrict__ cursor, __half* __restrict__ as_, int N) {
    int bid = blockIdx.x;
    int slice = bid & 7;
    int rb = bid >> 3;
    int r = rb * 128 + (threadIdx.x >> 1);
    if (r >= N) return;
    int h = threadIdx.x & 1;
    const int4* xi = (const int4*)xs + (size_t)slice * N * 2;
    int start = cursor[r];
    int end = cursor[r + 1];
    float4 a0 = zero4(), a1 = zero4();
    int e = start;
    for (; e + 4 <= end; e += 4) {
        int i0 = csr[e + 0], i1 = csr[e + 1], i2 = csr[e + 2], i3 = csr[e + 3];
        int4 v0 = xi[(size_t)i0 * 2 + h];
        int4 v1 = xi[(size_t)i1 * 2 + h];
        int4 v2 = xi[(size_t)i2 * 2 + h];
        int4 v3 = xi[(size_t)i3 * 2 + h];
        add_h8(a0, a1, v0); add_h8(a0, a1, v1);
        add_h8(a0, a1, v2); add_h8(a0, a1, v3);
    }
    for (; e < end; ++e) {
        int4 v0 = xi[(size_t)csr[e] * 2 + h];
        add_h8(a0, a1, v0);
    }
    ((int4*)as_)[(size_t)slice * N * 2 + (size_t)r * 2 + h] = pack_h8(a0, a1);
}

// ---------------- GEMM 128(fp16 slab agg) -> 128, epilogue acc*nd+bias, relu, (*ns) -> slabs --

template<int SCALE_NS>
__global__ __launch_bounds__(256, 6) void gemm128h(const __half* __restrict__ agg, const float* __restrict__ nd,
                                                   const float* __restrict__ ns, const float* __restrict__ W,
                                                   const float* __restrict__ bias, __half* __restrict__ out, int N) {
    __shared__ __half As[64 * AS_STRIDE];
    int t = threadIdx.x;
    int row0 = blockIdx.x * 64;

#pragma unroll
    for (int i = 0; i < 4; ++i) {
        int idx = t + 256 * i;          // 0..1023
        int s = idx >> 7;
        int rem = idx & 127;
        int r = rem >> 1;
        int h = rem & 1;
        int gr = row0 + r;
        int4 v = make_int4(0, 0, 0, 0);
        if (gr < N) v = ((const int4*)agg)[(size_t)s * N * 2 + (size_t)gr * 2 + h];
        *(int4*)&As[r * AS_STRIDE + (s * 2 + h) * 8] = v;
    }
    __syncthreads();

    int rg = t >> 4;
    int cgp = t & 15;
    int rbase = rg * 4;
    const float4* Wg = (const float4*)W;
    float4 acc[4][2];
#pragma unroll
    for (int m = 0; m < 4; ++m) { acc[m][0] = zero4(); acc[m][1] = zero4(); }
#pragma unroll 2
    for (int k4 = 0; k4 < 32; ++k4) {
        int k0 = k4 * 4;
        float4 a[4];
#pragma unroll
        for (int m = 0; m < 4; ++m) {
            uint2 raw = *(const uint2*)&As[(rbase + m) * AS_STRIDE + k0];
            const __half2* hp = (const __half2*)&raw;
            float2 f0 = __half22float2(hp[0]);
            float2 f1 = __half22float2(hp[1]);
            a[m] = make_float4(f0.x, f0.y, f1.x, f1.y);
        }
        float4 w[4][2];
#pragma unroll
        for (int j = 0; j < 4; ++j) {
            w[j][0] = Wg[(k0 + j) * 32 + cgp * 2 + 0];
            w[j][1] = Wg[(k0 + j) * 32 + cgp * 2 + 1];
        }
#pragma unroll
        for (int m = 0; m < 4; ++m) {
            fma4(acc[m][0], a[m].x, w[0][0]); fma4(acc[m][1], a[m].x, w[0][1]);
            fma4(acc[m][0], a[m].y, w[1][0]); fma4(acc[m][1], a[m].y, w[1][1]);
            fma4(acc[m][0], a[m].z, w[2][0]); fma4(acc[m][1], a[m].z, w[2][1]);
            fma4(acc[m][0], a[m].w, w[3][0]); fma4(acc[m][1], a[m].w, w[3][1]);
        }
    }

    float4 bb0 = ((const float4*)bias)[cgp * 2 + 0];
    float4 bb1 = ((const float4*)bias)[cgp * 2 + 1];
    int os = cgp >> 1, oh = cgp & 1;
#pragma unroll
    for (int m = 0; m < 4; ++m) {
        int gr = row0 + rbase + m;
        if (gr < N) {
            float ndr = nd[gr];
            float4 o0, o1;
            o0.x = fmaxf(fmaf(acc[m][0].x, ndr, bb0.x), 0.f);
            o0.y = fmaxf(fmaf(acc[m][0].y, ndr, bb0.y), 0.f);
            o0.z = fmaxf(fmaf(acc[m][0].z, ndr, bb0.z), 0.f);
            o0.w = fmaxf(fmaf(acc[m][0].w, ndr, bb0.w), 0.f);
            o1.x = fmaxf(fmaf(acc[m][1].x, ndr, bb1.x), 0.f);
            o1.y = fmaxf(fmaf(acc[m][1].y, ndr, bb1.y), 0.f);
            o1.z = fmaxf(fmaf(acc[m][1].z, ndr, bb1.z), 0.f);
            o1.w = fmaxf(fmaf(acc[m][1].w, ndr, bb1.w), 0.f);
            if (SCALE_NS) {
                float s = ns[gr];
                o0.x *= s; o0.y *= s; o0.z *= s; o0.w *= s;
                o1.x *= s; o1.y *= s; o1.z *= s; o1.w *= s;
            }
            ((int4*)out)[(size_t)os * N * 2 + (size_t)gr * 2 + oh] = pack_h8(o0, o1);
        }
    }
}

// ---------------- GEMM 128(slab fp16) -> 40, *ns, output 5 slabs of int4 (8 halves) ----------

__global__ __launch_bounds__(256) void gemm40_kernel(const __half* __restrict__ A, const float* __restrict__ W,
                                                     const float* __restrict__ ns, __half* __restrict__ y, int N) {
    __shared__ float Ws[128 * NCLS];   // 20 KB
    __shared__ float As[32 * 132];     // 16.5 KB
    __shared__ __half ys[32][40];      // 2.5 KB
    int t = threadIdx.x;
    int row0 = blockIdx.x * 32;

#pragma unroll
    for (int i = 0; i < 5; ++i) {
        int idx = t + 256 * i;
        ((float4*)Ws)[idx] = ((const float4*)W)[idx];
    }
#pragma unroll
    for (int i = 0; i < 2; ++i) {
        int idx = t + 256 * i;        // 0..511
        int s = idx >> 6;
        int rem = idx & 63;
        int r = rem >> 1;
        int h = rem & 1;
        int gr = row0 + r;
        int4 v = make_int4(0, 0, 0, 0);
        if (gr < N) v = ((const int4*)A)[(size_t)s * N * 2 + (size_t)gr * 2 + h];
        const __half2* hh = (const __half2*)&v;
        float2 f0 = __half22float2(hh[0]);
        float2 f1 = __half22float2(hh[1]);
        float2 f2 = __half22float2(hh[2]);
        float2 f3 = __half22float2(hh[3]);
        float* dp = &As[r * 132 + (s * 2 + h) * 8];
        dp[0] = f0.x; dp[1] = f0.y; dp[2] = f1.x; dp[3] = f1.y;
        dp[4] = f2.x; dp[5] = f2.y; dp[6] = f3.x; dp[7] = f3.y;
    }
    __syncthreads();

    int row = t >> 3;
    int cg = t & 7;
    float acc[5] = {0.f, 0.f, 0.f, 0.f, 0.f};
#pragma unroll 2
    for (int k4 = 0; k4 < 32; ++k4) {
        float4 a = *(const float4*)&As[row * 132 + k4 * 4];
#pragma unroll
        for (int j = 0; j < 4; ++j) {
            float av = (j == 0) ? a.x : (j == 1) ? a.y : (j == 2) ? a.z : a.w;
            const float* wp = &Ws[(k4 * 4 + j) * NCLS + cg * 5];
            acc[0] = fmaf(av, wp[0], acc[0]);
            acc[1] = fmaf(av, wp[1], acc[1]);
            acc[2] = fmaf(av, wp[2], acc[2]);
            acc[3] = fmaf(av, wp[3], acc[3]);
            acc[4] = fmaf(av, wp[4], acc[4]);
        }
    }
    {
        int gr = row0 + row;
        float s = (gr < N) ? ns[gr] : 0.f;
        __half* yp = &ys[row][cg * 5];
        yp[0] = __float2half_rn(acc[0] * s);
        yp[1] = __float2half_rn(acc[1] * s);
        yp[2] = __float2half_rn(acc[2] * s);
        yp[3] = __float2half_rn(acc[3] * s);
        yp[4] = __float2half_rn(acc[4] * s);
    }
    __syncthreads();
    if (t < 160) {
        int s = t >> 5;      // 0..4
        int r = t & 31;
        int gr = row0 + r;
        if (gr < N) ((int4*)y)[(size_t)s * N + gr] = *(const int4*)&ys[r][s * 8];
    }
}

// ---------------- slab gather 40-d + *nd + b2 -> out (fp32) ----------------
// grid = nrb256*8; slice = bid&7 (XCD-pinned; slices 5-7 idle). Slab = 1.6 MB, L2-resident.

__global__ __launch_bounds__(256) void gather40f(const __half* __restrict__ y, const int* __restrict__ csr,
                                                 const int* __restrict__ cursor, const float* __restrict__ nd,
                                                 const float* __restrict__ b2, float* __restrict__ out, int N) {
    int bid = blockIdx.x;
    int slice = bid & 7;
    if (slice >= 5) return;
    int rb = bid >> 3;
    int r = rb * 256 + threadIdx.x;
    if (r >= N) return;
    const int4* ys = (const int4*)y + (size_t)slice * N;
    int start = cursor[r];
    int end = cursor[r + 1];
    float4 a0 = zero4(), a1 = zero4();
    int e = start;
    for (; e + 4 <= end; e += 4) {
        int i0 = csr[e + 0], i1 = csr[e + 1], i2 = csr[e + 2], i3 = csr[e + 3];
        int4 v0 = ys[i0];
        int4 v1 = ys[i1];
        int4 v2 = ys[i2];
        int4 v3 = ys[i3];
        add_h8(a0, a1, v0); add_h8(a0, a1, v1);
        add_h8(a0, a1, v2); add_h8(a0, a1, v3);
    }
    for (; e < end; ++e) {
        int4 v0 = ys[csr[e]];
        add_h8(a0, a1, v0);
    }
    float s = nd[r];
    const float* bp = b2 + slice * 8;
    float4 o0, o1;
    o0.x = fmaf(a0.x, s, bp[0]); o0.y = fmaf(a0.y, s, bp[1]);
    o0.z = fmaf(a0.z, s, bp[2]); o0.w = fmaf(a0.w, s, bp[3]);
    o1.x = fmaf(a1.x, s, bp[4]); o1.y = fmaf(a1.y, s, bp[5]);
    o1.z = fmaf(a1.z, s, bp[6]); o1.w = fmaf(a1.w, s, bp[7]);
    float* op = out + (size_t)r * NCLS + slice * 8;
    *(float4*)(op + 0) = o0;
    *(float4*)(op + 4) = o1;
}

extern "C" void kernel_launch(void* const* d_in, const int* in_sizes, int n_in,
                              void* d_out, int out_size, void* d_ws, size_t ws_size,
                              hipStream_t stream) {
    const float* x  = (const float*)d_in[0];
    const int* src  = (const int*)d_in[1];
    const int* dst  = (const int*)d_in[2];
    const float* W0 = (const float*)d_in[3];
    const float* b0 = (const float*)d_in[4];
    const float* W1 = (const float*)d_in[5];
    const float* b1 = (const float*)d_in[6];
    const float* W2 = (const float*)d_in[7];
    const float* b2 = (const float*)d_in[8];
    float* out = (float*)d_out;

    int N = in_sizes[0] / IN_DIM;
    int E = in_sizes[1];

    float* base = (float*)d_ws;
    float* ns   = base;                       // N
    float* ndn  = base + (size_t)N;           // N
    int* dsg    = (int*)(base + 2 * (size_t)N);
    int* ddg    = dsg + (size_t)N;
    int* cursor = ddg + (size_t)N;            // N+1
    int* bsums  = cursor + (size_t)N + 1;     // 1024
    int* csr    = bsums + 1024;               // E
    __half* B0  = (__half*)(csr + (size_t)E); // N x 128 halves (slabs)
    __half* B1  = B0 + (size_t)N * 128;       // N x 128 halves (slabs)
    __half* B2  = B1 + (size_t)N * 128;       // N x 128 halves (slabs)
    __half* yh  = B2 + (size_t)N * 128;       // 5 slabs x N int4
    int* staging = (int*)B1;                  // 8*HB*SLICE_MAX ints, dead before B1 is written

    int nb = (N + 1023) / 1024;
    int gN = (N + 255) / 256;

    // degrees via sliced LDS histograms (no global atomics)
    hist_sliced<<<8 * HB, 256, 0, stream>>>(src, staging, E, N);
    reduce_staging<0><<<gN, 256, 0, stream>>>(staging, dsg, N);
    hist_sliced<<<8 * HB, 256, 0, stream>>>(dst, staging, E, N);
    reduce_staging<1><<<gN, 256, 0, stream>>>(staging, ddg, N);   // + exclusive prefix scanback
    norm_kernel<<<gN, 256, 0, stream>>>(dsg, ddg, ns, ndn, N);

    // row starts
    scan_partial<<<nb, 256, 0, stream>>>(ddg, bsums, N);
    scan_bsums<<<1, 128, 0, stream>>>(bsums, nb);
    scan_final<<<nb, 256, 0, stream>>>(ddg, bsums, cursor, N);

    // CSR fill: LDS cursors, plain csr stores
    fill_noatomic<<<8 * HB, 256, 0, stream>>>(src, dst, cursor, staging, csr, E, N);

    // B0 = slabbed fp16(x * ns)
    prescale_kernel<<<(N * 16 + 255) / 256, 256, 0, stream>>>(x, ns, B0, N);

    int nrb = (N + 127) / 128;
    int g64 = (N + 63) / 64;
    int nrb256 = (N + 255) / 256;

    // layer 0: B1 = spmm(B0) ; B2 = relu(B1*nd @ W0 + b0)*ns   (all slabbed)
    spmm16s<<<nrb * 8, 256, 0, stream>>>(B0, csr, cursor, B1, N);
    gemm128h<1><<<g64, 256, 0, stream>>>(B1, ndn, ns, W0, b0, B2, N);

    // layer 1: B1 = spmm(B2) ; B0 = relu(B1*nd @ W1 + b1)
    spmm16s<<<nrb * 8, 256, 0, stream>>>(B2, csr, cursor, B1, N);
    gemm128h<0><<<g64, 256, 0, stream>>>(B1, ndn, ns, W1, b1, B0, N);

    // layer 2: yh = (B0 @ W2)*ns (5 slabs) ; out = gather40(yh)*nd + b2
    gemm40_kernel<<<(N + 31) / 32, 256, 0, stream>>>(B0, W2, ns, yh, N);
    gather40f<<<nrb256 * 8, 256, 0, stream>>>(yh, csr, cursor, ndn, b2, out, N);
}